// Round 8
// baseline (380.581 us; speedup 1.0000x reference)
//
#include <hip/hip_runtime.h>
#include <cstdint>
#include <cstddef>

typedef unsigned short u16;
typedef __attribute__((ext_vector_type(8))) short short8;
typedef __attribute__((ext_vector_type(4))) short sv4;    // 4 bf16 frag
typedef __attribute__((ext_vector_type(4))) float f32x4;
typedef __attribute__((ext_vector_type(2))) unsigned int u32x2;
typedef __attribute__((ext_vector_type(4))) unsigned int u32x4;

__device__ __forceinline__ u16 f2bf(float f) {
  unsigned int u = __builtin_bit_cast(unsigned int, f);
  u += 0x7FFFu + ((u >> 16) & 1u);
  return (u16)(u >> 16);
}
__device__ __forceinline__ float bf2f(u16 v) {
  return __builtin_bit_cast(float, ((unsigned int)v) << 16);
}

// packed f32x2 -> bf16x2 (RNE). gfx950 has v_cvt_pk_bf16_f32; guard builtin
// probe with __HIP_DEVICE_COMPILE__ (host pass reports no amdgcn builtins, r7).
__device__ __forceinline__ unsigned int pk_bf16(float a, float b) {
#if defined(__HIP_DEVICE_COMPILE__) && __has_builtin(__builtin_amdgcn_cvt_pk_bf16_f32)
  typedef __attribute__((ext_vector_type(2))) __bf16 bf16x2;
  bf16x2 r = __builtin_amdgcn_cvt_pk_bf16_f32(a, b);
  return __builtin_bit_cast(unsigned int, r);
#else
  return (unsigned int)f2bf(a) | ((unsigned int)f2bf(b) << 16);
#endif
}

// 16x16x16 bf16 MFMA (device-gated probe — r7 lesson).
__device__ __forceinline__ f32x4 mfma_16x16x16_bf16(sv4 a, sv4 b, f32x4 c) {
#if defined(__HIP_DEVICE_COMPILE__)
#if __has_builtin(__builtin_amdgcn_mfma_f32_16x16x16bf16_1k)
  return __builtin_amdgcn_mfma_f32_16x16x16bf16_1k(a, b, c, 0, 0, 0);
#elif __has_builtin(__builtin_amdgcn_mfma_f32_16x16x16_bf16)
  return __builtin_amdgcn_mfma_f32_16x16x16_bf16(a, b, c, 0, 0, 0);
#else
  asm volatile("v_mfma_f32_16x16x16_bf16 %0, %1, %2, %0\n\ts_nop 7\n\ts_nop 4"
               : "+v"(c) : "v"(a), "v"(b));
  return c;
#endif
#else
  (void)a; (void)b;
  return c;   // host stub, never executed
#endif
}

// async global->LDS, 16B per lane; LDS dest = wave-uniform base + lane*16
// (used by the GEMMs, where it is proven fast on this harness)
#define GLD_LDS(g, l) __builtin_amdgcn_global_load_lds( \
    (const __attribute__((address_space(1))) void*)(g), \
    (__attribute__((address_space(3))) void*)(l), 16, 0, 0)

// (1/8) * log2(e): folded into Wq/bq at convert time so attn's exp2 needs no mul
#define QSCL 0.18033688011112042f

// ---------------------------------------------------------------------------
// dtype probe: flag 1 = fp32 inputs (established on this harness), 0 = bf16.
// ---------------------------------------------------------------------------
__global__ void detect_dtype(const u16* __restrict__ x, int* __restrict__ flag)
{
  const int lane = threadIdx.x;          // 64 threads
  int hit = 0;
#pragma unroll
  for (int j = 0; j < 4; ++j) {
    float v = bf2f(x[lane * 4 + j]);
    if (!(v > -1000.f && v < 1000.f)) hit = 1;
  }
  unsigned long long any = __ballot(hit != 0);
  if (lane == 0) *flag = (any != 0ull) ? 1 : 0;
}

// ---------------------------------------------------------------------------
// Convert weights+biases to bf16: Wc=[Wq|Wk|Wv|Wo], bc=[bq|bk|bv|bo].
// Wq and bq are pre-scaled by QSCL (softmax scale fold).
// ---------------------------------------------------------------------------
__global__ __launch_bounds__(256)
void convert_wb(const void* Wq, const void* Wk, const void* Wv, const void* Wo,
                const void* bq, const void* bk, const void* bv, const void* bo,
                u16* __restrict__ Wc, u16* __restrict__ bc, const int* __restrict__ flag)
{
  const int fp32 = *flag;
  const size_t base = ((size_t)blockIdx.x * 256 + threadIdx.x) * 8;
  const void* src; u16* dst; size_t local; int sel;
  if (base < (size_t)4 * 1048576) {
    sel = (int)(base >> 20);
    local = base & 1048575u;
    src = (sel == 0) ? Wq : (sel == 1) ? Wk : (sel == 2) ? Wv : Wo;
    dst = Wc + (size_t)sel * 1048576 + local;
  } else {
    const size_t rem = base - (size_t)4 * 1048576;   // 0..4095
    sel = (int)(rem >> 10);
    local = rem & 1023u;
    src = (sel == 0) ? bq : (sel == 1) ? bk : (sel == 2) ? bv : bo;
    dst = bc + (size_t)sel * 1024 + local;
  }
  const float scale = (sel == 0) ? QSCL : 1.0f;
  if (fp32) {
    const float* s = (const float*)src + local;
    u32x4 w;
#pragma unroll
    for (int j = 0; j < 4; ++j) w[j] = pk_bf16(s[2 * j] * scale, s[2 * j + 1] * scale);
    *(short8*)dst = __builtin_bit_cast(short8, w);
  } else {
    const u16* s = (const u16*)src + local;
    if (sel == 0) {
      u32x4 w;
#pragma unroll
      for (int j = 0; j < 4; ++j)
        w[j] = pk_bf16(bf2f(s[2 * j]) * scale, bf2f(s[2 * j + 1]) * scale);
      *(short8*)dst = __builtin_bit_cast(short8, w);
    } else {
      *(short8*)dst = *(const short8*)s;
    }
  }
}

// x convert: grid*256*8 elements from src element offset b*2097152; dst from 0.
__global__ __launch_bounds__(256)
void convert_x_off(const void* __restrict__ x, u16* __restrict__ dst,
                   const int* __restrict__ flag, int b)
{
  const int fp32 = *flag;
  const size_t base = ((size_t)blockIdx.x * 256 + threadIdx.x) * 8;
  const size_t src_e = (size_t)b * 2048 * 1024 + base;
  if (fp32) {
    const float* s = (const float*)x + src_e;
    u32x4 w;
#pragma unroll
    for (int j = 0; j < 4; ++j) w[j] = pk_bf16(s[2 * j], s[2 * j + 1]);
    *(short8*)(dst + base) = __builtin_bit_cast(short8, w);
  } else {
    *(short8*)(dst + base) = *(const short8*)((const u16*)x + src_e);
  }
}

// ---------------------------------------------------------------------------
// GEMM (bf16 in/out): C[m,n] = sum_k A[m,k]*B[n,k] + bias[sel*1024 + n%1024].
// 128x128 tile, BK=32, 4 waves each 64x64 (m97 structure).
// r9: blockIdx.x = m-tile (fast) so concurrent blocks share one B panel in L2.
// ---------------------------------------------------------------------------
__global__ __launch_bounds__(256)
void gemm_bt(const u16* __restrict__ A,
             const u16* __restrict__ B0, const u16* __restrict__ B1, const u16* __restrict__ B2,
             const u16* __restrict__ bias, u16* __restrict__ C, int Ntot, int K)
{
  __shared__ __align__(16) u16 Alds[128 * 32];
  __shared__ __align__(16) u16 Blds[128 * 32];
  const int tid  = threadIdx.x;
  const int wave = tid >> 6, lane = tid & 63;
  const int quad = lane >> 4, l15 = lane & 15;
  const int m0  = blockIdx.x * 128;        // m fast-varying (L2 B-panel reuse)
  const int n0g = blockIdx.y * 128;
  const int sel = n0g >> 10;
  const u16* Bm = (sel == 0) ? B0 : ((sel == 1) ? B1 : B2);
  const u16* bb = bias + (size_t)sel * 1024;
  const int n0 = n0g & 1023;
  const int wr = (wave >> 1) * 64, wc = (wave & 1) * 64;

  f32x4 acc[4][4] = {};
  const int srow = lane >> 2;        // 0..15
  const int skc  = (lane & 3) * 8;   // 16B k-chunk
  const u16* Ag = A  + (size_t)(m0 + srow) * K + skc;
  const u16* Bg = Bm + (size_t)(n0 + srow) * K + skc;

  for (int kt = 0; kt < K; kt += 32) {
    __syncthreads();
#pragma unroll
    for (int t = 0; t < 2; ++t) {
      const int seg = wave * 2 + t;
      GLD_LDS(Ag + (size_t)(seg * 16) * K + kt, Alds + seg * 512);
      GLD_LDS(Bg + (size_t)(seg * 16) * K + kt, Blds + seg * 512);
    }
    __syncthreads();

    short8 af[4], bfr[4];
#pragma unroll
    for (int i = 0; i < 4; ++i)
      af[i] = *(const short8*)&Alds[(wr + i * 16 + l15) * 32 + quad * 8];
#pragma unroll
    for (int j = 0; j < 4; ++j)
      bfr[j] = *(const short8*)&Blds[(wc + j * 16 + l15) * 32 + quad * 8];
#pragma unroll
    for (int i = 0; i < 4; ++i)
#pragma unroll
      for (int j = 0; j < 4; ++j)
        acc[i][j] = __builtin_amdgcn_mfma_f32_16x16x32_bf16(af[i], bfr[j], acc[i][j], 0, 0, 0);
  }

#pragma unroll
  for (int i = 0; i < 4; ++i) {
    const int mr = m0 + wr + i * 16 + quad * 4;
#pragma unroll
    for (int j = 0; j < 4; ++j) {
      const int ncl = wc + j * 16 + l15;
      const float bvv = bf2f(bb[n0 + ncl]);
#pragma unroll
      for (int r = 0; r < 4; ++r)
        C[(size_t)(mr + r) * Ntot + n0g + ncl] = f2bf(acc[i][j][r] + bvv);
    }
  }
}

// ---------------------------------------------------------------------------
// Out-proj GEMM: writes d_out in dtype chosen by *flag. m-tile fast (r9).
// ---------------------------------------------------------------------------
__global__ __launch_bounds__(256)
void gemm_bt_out(const u16* __restrict__ A, const u16* __restrict__ Bm,
                 const u16* __restrict__ bias, void* __restrict__ C16,
                 void* __restrict__ C32, int Ntot, int K, const int* __restrict__ flag)
{
  __shared__ __align__(16) u16 Alds[128 * 32];
  __shared__ __align__(16) u16 Blds[128 * 32];
  const int tid  = threadIdx.x;
  const int wave = tid >> 6, lane = tid & 63;
  const int quad = lane >> 4, l15 = lane & 15;
  const int m0 = blockIdx.x * 128;
  const int n0 = blockIdx.y * 128;
  const int wr = (wave >> 1) * 64, wc = (wave & 1) * 64;

  f32x4 acc[4][4] = {};
  const int srow = lane >> 2;
  const int skc  = (lane & 3) * 8;
  const u16* Ag = A  + (size_t)(m0 + srow) * K + skc;
  const u16* Bg = Bm + (size_t)(n0 + srow) * K + skc;

  for (int kt = 0; kt < K; kt += 32) {
    __syncthreads();
#pragma unroll
    for (int t = 0; t < 2; ++t) {
      const int seg = wave * 2 + t;
      GLD_LDS(Ag + (size_t)(seg * 16) * K + kt, Alds + seg * 512);
      GLD_LDS(Bg + (size_t)(seg * 16) * K + kt, Blds + seg * 512);
    }
    __syncthreads();

    short8 af[4], bfr[4];
#pragma unroll
    for (int i = 0; i < 4; ++i)
      af[i] = *(const short8*)&Alds[(wr + i * 16 + l15) * 32 + quad * 8];
#pragma unroll
    for (int j = 0; j < 4; ++j)
      bfr[j] = *(const short8*)&Blds[(wc + j * 16 + l15) * 32 + quad * 8];
#pragma unroll
    for (int i = 0; i < 4; ++i)
#pragma unroll
      for (int j = 0; j < 4; ++j)
        acc[i][j] = __builtin_amdgcn_mfma_f32_16x16x32_bf16(af[i], bfr[j], acc[i][j], 0, 0, 0);
  }

  if (*flag != 0) {
    float* Cf = (float*)C32;
#pragma unroll
    for (int i = 0; i < 4; ++i) {
      const int mr = m0 + wr + i * 16 + quad * 4;
#pragma unroll
      for (int j = 0; j < 4; ++j) {
        const int ncl = wc + j * 16 + l15;
        const float bvv = bf2f(bias[n0 + ncl]);
#pragma unroll
        for (int r = 0; r < 4; ++r)
          Cf[(size_t)(mr + r) * Ntot + n0 + ncl] = acc[i][j][r] + bvv;
      }
    }
  } else {
    u16* Cb = (u16*)C16;
#pragma unroll
    for (int i = 0; i < 4; ++i) {
      const int mr = m0 + wr + i * 16 + quad * 4;
#pragma unroll
      for (int j = 0; j < 4; ++j) {
        const int ncl = wc + j * 16 + l15;
        const float bvv = bf2f(bias[n0 + ncl]);
#pragma unroll
        for (int r = 0; r < 4; ++r)
          Cb[(size_t)(mr + r) * Ntot + n0 + ncl] = f2bf(acc[i][j][r] + bvv);
      }
    }
  }
}

// ---------------------------------------------------------------------------
// Flash attention, S^T formulation (register-resident P). Q pre-scaled by
// QSCL at the projection, so exp2 applies directly to sacc.
//
// r7 post-mortem: staged regs held across ATILE -> scratch (WRITE 244MB);
// within-thread register prefetch across the MFMA blob is structurally
// unavailable (r5 had identical signature). HARD CONSTRAINT.
// r8 = r6 base (118.7us, FETCH 24.6MB, proven) minus staging work:
//  * K read DIRECT from global in the MFMA phase (common-mistake #7 / m169:
//    K is L2/L3-resident — FETCH 24.6MB proves it; all 8 waves read the SAME
//    K tile, so 1 L2 miss + 7 L1 hits per line; K slice 8KB/head fits L1).
//    Removes K loads, 8-way-conflicted K ds_writes, kf ds_reads, 18KB LDS.
//  * V staging spread over all 512 threads (2x8B loads + 4 packs each, half
//    of r6's per-thread work), load->pack->write immediate (no spill).
//  * V double-buffered with SYNCHRONOUS staging: {stage B; compute A; bar;
//    stage A; compute B; bar} -> 1 barrier/tile (was 2), no regs across
//    compute. LDS = 2x8KB.
// Compute/softmax/PV/store byte-identical to r6.
// Tripwire: WRITE_SIZE >> 20MB => revert to r6 verbatim.
// ---------------------------------------------------------------------------

// stage one 64-kv V tile into VL (all 512 threads; immediate load->pack->write)
#define VSTAGE(VL) do {                                                        \
    const sv4 v0 = *(const sv4*)vgp;                                           \
    const sv4 v1 = *(const sv4*)(vgp + 3072);                                  \
    _Pragma("unroll")                                                          \
    for (int jj = 0; jj < 4; ++jj) {                                           \
      const int d = d0v + jj;                                                  \
      (VL)[d * 32 + ((kb ^ (d & 15)) << 1) + kl] =                             \
          ((unsigned int)(unsigned short)v0[jj]) |                             \
          (((unsigned int)(unsigned short)v1[jj]) << 16);                      \
    }                                                                          \
    vgp += ADV;                                                                \
  } while (0)

// compute one 64-kv tile: K direct from global (Ktp), V from LDS (VL)
#define ATILE(VL) do {                                                         \
    f32x4 sacc[4][2] = {};                                                     \
    _Pragma("unroll")                                                          \
    for (int kh = 0; kh < 2; ++kh) {                                           \
      short8 kf[4];                                                            \
      _Pragma("unroll")                                                        \
      for (int ct = 0; ct < 4; ++ct)                                           \
        kf[ct] = *(const short8*)(Ktp + (size_t)(ct * 16) * 3072 + kh * 32);   \
      __builtin_amdgcn_s_setprio(1);                                           \
      _Pragma("unroll")                                                        \
      for (int ct = 0; ct < 4; ++ct)                                           \
        _Pragma("unroll")                                                      \
        for (int rt = 0; rt < 2; ++rt)                                         \
          sacc[ct][rt] = __builtin_amdgcn_mfma_f32_16x16x32_bf16(              \
              kf[ct], qf[rt][kh], sacc[ct][rt], 0, 0, 0);                      \
      __builtin_amdgcn_s_setprio(0);                                           \
    }                                                                          \
    Ktp += ADV;                                                                \
    sv4 p16[4][2];                                                             \
    _Pragma("unroll")                                                          \
    for (int rt = 0; rt < 2; ++rt) {                                           \
      float rs = 0.f;                                                          \
      _Pragma("unroll")                                                        \
      for (int ct = 0; ct < 4; ++ct) {                                         \
        float p0 = __builtin_amdgcn_exp2f(sacc[ct][rt][0]);                    \
        float p1 = __builtin_amdgcn_exp2f(sacc[ct][rt][1]);                    \
        float p2 = __builtin_amdgcn_exp2f(sacc[ct][rt][2]);                    \
        float p3 = __builtin_amdgcn_exp2f(sacc[ct][rt][3]);                    \
        rs += (p0 + p1) + (p2 + p3);                                           \
        u32x2 pw;                                                              \
        pw[0] = pk_bf16(p0, p1);                                               \
        pw[1] = pk_bf16(p2, p3);                                               \
        p16[ct][rt] = __builtin_bit_cast(sv4, pw);                             \
      }                                                                        \
      rs += __shfl_xor(rs, 16, 64);                                            \
      rs += __shfl_xor(rs, 32, 64);                                            \
      lrow[rt] += rs;                                                          \
    }                                                                          \
    __builtin_amdgcn_s_setprio(1);                                             \
    _Pragma("unroll")                                                          \
    for (int ct = 0; ct < 4; ++ct) {                                           \
      _Pragma("unroll")                                                        \
      for (int dt = 0; dt < 4; ++dt) {                                         \
        const int d = dt * 16 + l15;                                           \
        const int idx = d * 32 + (((ct * 4 + quad) ^ (d & 15)) << 1);          \
        const sv4 vfr = *(const sv4*)&(VL)[idx];                               \
        _Pragma("unroll")                                                      \
        for (int rt = 0; rt < 2; ++rt)                                         \
          oaccT[dt][rt] = mfma_16x16x16_bf16(vfr, p16[ct][rt], oaccT[dt][rt]); \
      }                                                                        \
    }                                                                          \
    __builtin_amdgcn_s_setprio(0);                                             \
  } while (0)

__global__ __launch_bounds__(512, 4)
void attn_s(const u16* __restrict__ QKV, u16* __restrict__ O)
{
  __shared__ __align__(16) unsigned int Va[64 * 32], Vb[64 * 32];  // 8KB each
  const int tid  = threadIdx.x;
  const int wave = tid >> 6, lane = tid & 63;
  const int quad = lane >> 4, l15 = lane & 15;

  // XCD-panel swizzle: all 8 qt of a panel -> same XCD, consecutive slots.
  const int i  = blockIdx.x;
  const int j  = i >> 3;
  const int qt = j & 7;
  const int g  = (i & 7) + ((j >> 3) << 3);      // panel id = h + 16*z
  const int h  = g & 15;
  const int z  = g >> 4;

  const u16* QKVb = QKV + (size_t)z * 2048 * 3072;
  u16* Ob = O + (size_t)z * 2048 * 1024;
  const int q0 = qt * 256;

  // Q fragments (B-operand of x32: n=l15 -> q, k=quad*8+jj -> d)
  short8 qf[2][2];
  const u16* Qb = QKVb + (size_t)(q0 + wave * 32) * 3072 + h * 64;
#pragma unroll
  for (int rt = 0; rt < 2; ++rt)
#pragma unroll
    for (int kh = 0; kh < 2; ++kh)
      qf[rt][kh] = *(const short8*)(Qb + (size_t)(rt * 16 + l15) * 3072 + kh * 32 + quad * 8);

  f32x4 oaccT[4][2] = {};    // [dt][rt]: C[m=d_local][n=q]
  float lrow[2] = {};

  // K direct-read pointer: row l15 within tile, byte col quad*16 + kh*64
  const u16* Ktp = QKVb + 1024 + h * 64 + (size_t)l15 * 3072 + quad * 8;

  // V staging ids — all 512 threads: pair p = tid&31 (kv rows 2p, 2p+1),
  // d-group d0v = (tid>>5)*4  (16 groups x 4 d-values = 64)
  const int d0v = (tid >> 5) * 4;
  const int kb  = (tid >> 1) & 15;     // p>>1
  const int kl  = tid & 1;             // p&1
  const u16* vgp = QKVb + 2048 + h * 64 + (size_t)(2 * (tid & 31)) * 3072 + d0v;
  const size_t ADV = (size_t)64 * 3072;

  VSTAGE(Va);                  // tile 0
  __syncthreads();             // buf A visible
#pragma unroll 1
  for (int itp = 0; itp < 16; ++itp) {
    VSTAGE(Vb);                // tile 2*itp+1 (writes B; readers of B done)
    ATILE(Va);                 // tile 2*itp   (reads A)
    __syncthreads();           // B staged by all; all done reading A
    if (itp != 15) VSTAGE(Va); // tile 2*itp+2
    ATILE(Vb);                 // tile 2*itp+1
    __syncthreads();           // A staged; all done reading B
  }

  // store O[q][d]: q = q0+wave*32+rt*16+l15 (col), d = dt*16+quad*4+r (row)
#pragma unroll
  for (int rt = 0; rt < 2; ++rt) {
    const float inv = 1.f / lrow[rt];
    u16* Op = Ob + (size_t)(q0 + wave * 32 + rt * 16 + l15) * 1024 + h * 64;
#pragma unroll
    for (int dt = 0; dt < 4; ++dt) {
      u32x2 ow;
      ow[0] = pk_bf16(oaccT[dt][rt][0] * inv, oaccT[dt][rt][1] * inv);
      ow[1] = pk_bf16(oaccT[dt][rt][2] * inv, oaccT[dt][rt][3] * inv);
      *(sv4*)(Op + dt * 16 + quad * 4) = __builtin_bit_cast(sv4, ow);
    }
  }
}

// ---------------------------------------------------------------------------
extern "C" void kernel_launch(void* const* d_in, const int* in_sizes, int n_in,
                              void* d_out, int out_size, void* d_ws, size_t ws_size,
                              hipStream_t stream)
{
  // Common: flag + converted weights.
  int* flag = (int*)d_ws;
  u16* Wc   = (u16*)((char*)d_ws + 256);
  u16* bc   = Wc + (size_t)4 * 1048576;           // 4M u16
  char* after_wb = (char*)(bc + 4096);

  detect_dtype<<<1, 64, 0, stream>>>((const u16*)d_in[0], flag);
  convert_wb<<<2050, 256, 0, stream>>>(d_in[1], d_in[3], d_in[5], d_in[7],
                                       d_in[2], d_in[4], d_in[6], d_in[8],
                                       Wc, bc, flag);

  const size_t need_batched =
      (size_t)(after_wb - (char*)d_ws) + ((size_t)8192 * 3072 + (size_t)8192 * 1024) * 2;

  if (ws_size >= need_batched) {
    // ---- batched path: one launch per stage, full-device grids ----
    u16* QKV = (u16*)after_wb;
    u16* xO  = QKV + (size_t)8192 * 3072;   // xc before QKV-GEMM; O after attn

    convert_x_off<<<4096, 256, 0, stream>>>(d_in[0], xO, flag, 0);
    gemm_bt<<<dim3(64, 24), 256, 0, stream>>>(xO, Wc, Wc + 1048576, Wc + 2097152,
                                              bc, QKV, 3072, 1024);
    attn_s<<<512, 512, 0, stream>>>(QKV, xO);
    gemm_bt_out<<<dim3(64, 8), 256, 0, stream>>>(xO, Wc + (size_t)3 * 1048576,
                                                 bc + 3 * 1024, d_out, d_out,
                                                 1024, 1024, flag);
  } else {
    // ---- fallback: per-batch path (ws ~29.4 MB, proven) ----
    u16* xc   = (u16*)after_wb;
    u16* QKVb = xc + (size_t)2048 * 1024;
    u16* Obb  = QKVb + (size_t)2048 * 3072;
    for (int b = 0; b < 4; ++b) {
      convert_x_off<<<1024, 256, 0, stream>>>(d_in[0], xc, flag, b);
      gemm_bt<<<dim3(16, 24), 256, 0, stream>>>(xc, Wc, Wc + 1048576, Wc + 2097152,
                                                bc, QKVb, 3072, 1024);
      attn_s<<<128, 512, 0, stream>>>(QKVb, Obb);
      void* outb16 = (void*)((char*)d_out + (size_t)b * 2048 * 1024 * 2);
      void* outb32 = (void*)((char*)d_out + (size_t)b * 2048 * 1024 * 4);
      gemm_bt_out<<<dim3(16, 8), 256, 0, stream>>>(Obb, Wc + (size_t)3 * 1048576,
                                                   bc + 3 * 1024, outb16, outb32,
                                                   1024, 1024, flag);
    }
  }
}

// Round 11
// 327.200 us; speedup vs baseline: 1.1631x; 1.1631x over previous
//
#include <hip/hip_runtime.h>
#include <cstdint>
#include <cstddef>

typedef unsigned short u16;
typedef __attribute__((ext_vector_type(8))) short short8;
typedef __attribute__((ext_vector_type(4))) short sv4;    // 4 bf16 frag
typedef __attribute__((ext_vector_type(4))) float f32x4;
typedef __attribute__((ext_vector_type(2))) unsigned int u32x2;
typedef __attribute__((ext_vector_type(4))) unsigned int u32x4;

__device__ __forceinline__ u16 f2bf(float f) {
  unsigned int u = __builtin_bit_cast(unsigned int, f);
  u += 0x7FFFu + ((u >> 16) & 1u);
  return (u16)(u >> 16);
}
__device__ __forceinline__ float bf2f(u16 v) {
  return __builtin_bit_cast(float, ((unsigned int)v) << 16);
}

// packed f32x2 -> bf16x2 (RNE). gfx950 has v_cvt_pk_bf16_f32; guard builtin
// probe with __HIP_DEVICE_COMPILE__ (host pass reports no amdgcn builtins, r7).
__device__ __forceinline__ unsigned int pk_bf16(float a, float b) {
#if defined(__HIP_DEVICE_COMPILE__) && __has_builtin(__builtin_amdgcn_cvt_pk_bf16_f32)
  typedef __attribute__((ext_vector_type(2))) __bf16 bf16x2;
  bf16x2 r = __builtin_amdgcn_cvt_pk_bf16_f32(a, b);
  return __builtin_bit_cast(unsigned int, r);
#else
  return (unsigned int)f2bf(a) | ((unsigned int)f2bf(b) << 16);
#endif
}

// 16x16x16 bf16 MFMA (device-gated probe — r7 lesson).
__device__ __forceinline__ f32x4 mfma_16x16x16_bf16(sv4 a, sv4 b, f32x4 c) {
#if defined(__HIP_DEVICE_COMPILE__)
#if __has_builtin(__builtin_amdgcn_mfma_f32_16x16x16bf16_1k)
  return __builtin_amdgcn_mfma_f32_16x16x16bf16_1k(a, b, c, 0, 0, 0);
#elif __has_builtin(__builtin_amdgcn_mfma_f32_16x16x16_bf16)
  return __builtin_amdgcn_mfma_f32_16x16x16_bf16(a, b, c, 0, 0, 0);
#else
  asm volatile("v_mfma_f32_16x16x16_bf16 %0, %1, %2, %0\n\ts_nop 7\n\ts_nop 4"
               : "+v"(c) : "v"(a), "v"(b));
  return c;
#endif
#else
  (void)a; (void)b;
  return c;   // host stub, never executed
#endif
}

// async global->LDS, 16B per lane; LDS dest = wave-uniform base + lane*16
// (used by the GEMMs, where it is proven fast on this harness)
#define GLD_LDS(g, l) __builtin_amdgcn_global_load_lds( \
    (const __attribute__((address_space(1))) void*)(g), \
    (__attribute__((address_space(3))) void*)(l), 16, 0, 0)

// (1/8) * log2(e): folded into Wq/bq at convert time so attn's exp2 needs no mul
#define QSCL 0.18033688011112042f

// ---------------------------------------------------------------------------
// dtype probe: flag 1 = fp32 inputs (established on this harness), 0 = bf16.
// ---------------------------------------------------------------------------
__global__ void detect_dtype(const u16* __restrict__ x, int* __restrict__ flag)
{
  const int lane = threadIdx.x;          // 64 threads
  int hit = 0;
#pragma unroll
  for (int j = 0; j < 4; ++j) {
    float v = bf2f(x[lane * 4 + j]);
    if (!(v > -1000.f && v < 1000.f)) hit = 1;
  }
  unsigned long long any = __ballot(hit != 0);
  if (lane == 0) *flag = (any != 0ull) ? 1 : 0;
}

// ---------------------------------------------------------------------------
// Convert weights+biases to bf16: Wc=[Wq|Wk|Wv|Wo], bc=[bq|bk|bv|bo].
// Wq and bq are pre-scaled by QSCL (softmax scale fold).
// ---------------------------------------------------------------------------
__global__ __launch_bounds__(256)
void convert_wb(const void* Wq, const void* Wk, const void* Wv, const void* Wo,
                const void* bq, const void* bk, const void* bv, const void* bo,
                u16* __restrict__ Wc, u16* __restrict__ bc, const int* __restrict__ flag)
{
  const int fp32 = *flag;
  const size_t base = ((size_t)blockIdx.x * 256 + threadIdx.x) * 8;
  const void* src; u16* dst; size_t local; int sel;
  if (base < (size_t)4 * 1048576) {
    sel = (int)(base >> 20);
    local = base & 1048575u;
    src = (sel == 0) ? Wq : (sel == 1) ? Wk : (sel == 2) ? Wv : Wo;
    dst = Wc + (size_t)sel * 1048576 + local;
  } else {
    const size_t rem = base - (size_t)4 * 1048576;   // 0..4095
    sel = (int)(rem >> 10);
    local = rem & 1023u;
    src = (sel == 0) ? bq : (sel == 1) ? bk : (sel == 2) ? bv : bo;
    dst = bc + (size_t)sel * 1024 + local;
  }
  const float scale = (sel == 0) ? QSCL : 1.0f;
  if (fp32) {
    const float* s = (const float*)src + local;
    u32x4 w;
#pragma unroll
    for (int j = 0; j < 4; ++j) w[j] = pk_bf16(s[2 * j] * scale, s[2 * j + 1] * scale);
    *(short8*)dst = __builtin_bit_cast(short8, w);
  } else {
    const u16* s = (const u16*)src + local;
    if (sel == 0) {
      u32x4 w;
#pragma unroll
      for (int j = 0; j < 4; ++j)
        w[j] = pk_bf16(bf2f(s[2 * j]) * scale, bf2f(s[2 * j + 1]) * scale);
      *(short8*)dst = __builtin_bit_cast(short8, w);
    } else {
      *(short8*)dst = *(const short8*)s;
    }
  }
}

// x convert: grid*256*8 elements from src element offset b*2097152; dst from 0.
__global__ __launch_bounds__(256)
void convert_x_off(const void* __restrict__ x, u16* __restrict__ dst,
                   const int* __restrict__ flag, int b)
{
  const int fp32 = *flag;
  const size_t base = ((size_t)blockIdx.x * 256 + threadIdx.x) * 8;
  const size_t src_e = (size_t)b * 2048 * 1024 + base;
  if (fp32) {
    const float* s = (const float*)x + src_e;
    u32x4 w;
#pragma unroll
    for (int j = 0; j < 4; ++j) w[j] = pk_bf16(s[2 * j], s[2 * j + 1]);
    *(short8*)(dst + base) = __builtin_bit_cast(short8, w);
  } else {
    *(short8*)(dst + base) = *(const short8*)((const u16*)x + src_e);
  }
}

// ---------------------------------------------------------------------------
// GEMM (bf16 in/out): C[m,n] = sum_k A[m,k]*B[n,k] + bias[sel*1024 + n%1024].
// 128x128 tile, BK=32, 4 waves each 64x64 (m97 structure).
// r9: blockIdx.x = m-tile (fast) so concurrent blocks share one B panel in L2.
// ---------------------------------------------------------------------------
__global__ __launch_bounds__(256)
void gemm_bt(const u16* __restrict__ A,
             const u16* __restrict__ B0, const u16* __restrict__ B1, const u16* __restrict__ B2,
             const u16* __restrict__ bias, u16* __restrict__ C, int Ntot, int K)
{
  __shared__ __align__(16) u16 Alds[128 * 32];
  __shared__ __align__(16) u16 Blds[128 * 32];
  const int tid  = threadIdx.x;
  const int wave = tid >> 6, lane = tid & 63;
  const int quad = lane >> 4, l15 = lane & 15;
  const int m0  = blockIdx.x * 128;        // m fast-varying (L2 B-panel reuse)
  const int n0g = blockIdx.y * 128;
  const int sel = n0g >> 10;
  const u16* Bm = (sel == 0) ? B0 : ((sel == 1) ? B1 : B2);
  const u16* bb = bias + (size_t)sel * 1024;
  const int n0 = n0g & 1023;
  const int wr = (wave >> 1) * 64, wc = (wave & 1) * 64;

  f32x4 acc[4][4] = {};
  const int srow = lane >> 2;        // 0..15
  const int skc  = (lane & 3) * 8;   // 16B k-chunk
  const u16* Ag = A  + (size_t)(m0 + srow) * K + skc;
  const u16* Bg = Bm + (size_t)(n0 + srow) * K + skc;

  for (int kt = 0; kt < K; kt += 32) {
    __syncthreads();
#pragma unroll
    for (int t = 0; t < 2; ++t) {
      const int seg = wave * 2 + t;
      GLD_LDS(Ag + (size_t)(seg * 16) * K + kt, Alds + seg * 512);
      GLD_LDS(Bg + (size_t)(seg * 16) * K + kt, Blds + seg * 512);
    }
    __syncthreads();

    short8 af[4], bfr[4];
#pragma unroll
    for (int i = 0; i < 4; ++i)
      af[i] = *(const short8*)&Alds[(wr + i * 16 + l15) * 32 + quad * 8];
#pragma unroll
    for (int j = 0; j < 4; ++j)
      bfr[j] = *(const short8*)&Blds[(wc + j * 16 + l15) * 32 + quad * 8];
#pragma unroll
    for (int i = 0; i < 4; ++i)
#pragma unroll
      for (int j = 0; j < 4; ++j)
        acc[i][j] = __builtin_amdgcn_mfma_f32_16x16x32_bf16(af[i], bfr[j], acc[i][j], 0, 0, 0);
  }

#pragma unroll
  for (int i = 0; i < 4; ++i) {
    const int mr = m0 + wr + i * 16 + quad * 4;
#pragma unroll
    for (int j = 0; j < 4; ++j) {
      const int ncl = wc + j * 16 + l15;
      const float bvv = bf2f(bb[n0 + ncl]);
#pragma unroll
      for (int r = 0; r < 4; ++r)
        C[(size_t)(mr + r) * Ntot + n0g + ncl] = f2bf(acc[i][j][r] + bvv);
    }
  }
}

// ---------------------------------------------------------------------------
// Out-proj GEMM: writes d_out in dtype chosen by *flag. m-tile fast (r9).
// ---------------------------------------------------------------------------
__global__ __launch_bounds__(256)
void gemm_bt_out(const u16* __restrict__ A, const u16* __restrict__ Bm,
                 const u16* __restrict__ bias, void* __restrict__ C16,
                 void* __restrict__ C32, int Ntot, int K, const int* __restrict__ flag)
{
  __shared__ __align__(16) u16 Alds[128 * 32];
  __shared__ __align__(16) u16 Blds[128 * 32];
  const int tid  = threadIdx.x;
  const int wave = tid >> 6, lane = tid & 63;
  const int quad = lane >> 4, l15 = lane & 15;
  const int m0 = blockIdx.x * 128;
  const int n0 = blockIdx.y * 128;
  const int wr = (wave >> 1) * 64, wc = (wave & 1) * 64;

  f32x4 acc[4][4] = {};
  const int srow = lane >> 2;
  const int skc  = (lane & 3) * 8;
  const u16* Ag = A  + (size_t)(m0 + srow) * K + skc;
  const u16* Bg = Bm + (size_t)(n0 + srow) * K + skc;

  for (int kt = 0; kt < K; kt += 32) {
    __syncthreads();
#pragma unroll
    for (int t = 0; t < 2; ++t) {
      const int seg = wave * 2 + t;
      GLD_LDS(Ag + (size_t)(seg * 16) * K + kt, Alds + seg * 512);
      GLD_LDS(Bg + (size_t)(seg * 16) * K + kt, Blds + seg * 512);
    }
    __syncthreads();

    short8 af[4], bfr[4];
#pragma unroll
    for (int i = 0; i < 4; ++i)
      af[i] = *(const short8*)&Alds[(wr + i * 16 + l15) * 32 + quad * 8];
#pragma unroll
    for (int j = 0; j < 4; ++j)
      bfr[j] = *(const short8*)&Blds[(wc + j * 16 + l15) * 32 + quad * 8];
#pragma unroll
    for (int i = 0; i < 4; ++i)
#pragma unroll
      for (int j = 0; j < 4; ++j)
        acc[i][j] = __builtin_amdgcn_mfma_f32_16x16x32_bf16(af[i], bfr[j], acc[i][j], 0, 0, 0);
  }

  if (*flag != 0) {
    float* Cf = (float*)C32;
#pragma unroll
    for (int i = 0; i < 4; ++i) {
      const int mr = m0 + wr + i * 16 + quad * 4;
#pragma unroll
      for (int j = 0; j < 4; ++j) {
        const int ncl = wc + j * 16 + l15;
        const float bvv = bf2f(bias[n0 + ncl]);
#pragma unroll
        for (int r = 0; r < 4; ++r)
          Cf[(size_t)(mr + r) * Ntot + n0 + ncl] = acc[i][j][r] + bvv;
      }
    }
  } else {
    u16* Cb = (u16*)C16;
#pragma unroll
    for (int i = 0; i < 4; ++i) {
      const int mr = m0 + wr + i * 16 + quad * 4;
#pragma unroll
      for (int j = 0; j < 4; ++j) {
        const int ncl = wc + j * 16 + l15;
        const float bvv = bf2f(bias[n0 + ncl]);
#pragma unroll
        for (int r = 0; r < 4; ++r)
          Cb[(size_t)(mr + r) * Ntot + n0 + ncl] = f2bf(acc[i][j][r] + bvv);
      }
    }
  }
}

// ---------------------------------------------------------------------------
// Flash attention, S^T formulation (register-resident P). Q pre-scaled by
// QSCL at the projection, so exp2 applies directly to sacc.
//
// r9 RESUBMIT #2: two harness-level failures with different infra signatures
// (Trio ExceptionGroup; container-acquire failed twice). Kernel audited clean
// three times: schedule shape hardware-proven by r8 (passed); memory-safe
// (max row 2047, bijective V write map identical to r8); no divergent
// barriers; 34KB LDS x4 blocks/CU fits. Contingency: a third failure means
// revert to r6 verbatim and abandon this lever.
//
// Design: r6's layouts/compute byte-for-byte + synchronous double-buffer
// ({STAGE(B); ATILE(A); bar; STAGE(A); ATILE(B); bar} — a stalling stager
// overlaps the other 7 waves' ATILEs; 1 barrier/tile) and staging spread
// over all 512 threads (1x16B K chunk + r8's proven V pack per thread).
// Tripwire: WRITE >> 20MB = spill => revert to r6 verbatim.
// ---------------------------------------------------------------------------

// stage one 64-kv tile (all 512 threads; loads -> immediate writes)
#define STAGE(KL, VL) do {                                                     \
    const short8 kv16 = *(const short8*)kgp;                                   \
    const sv4 v0 = *(const sv4*)vgp;                                           \
    const sv4 v1 = *(const sv4*)(vgp + 3072);                                  \
    *(short8*)&(KL)[kwoff] = kv16;                                             \
    _Pragma("unroll")                                                          \
    for (int jj = 0; jj < 4; ++jj) {                                           \
      const int d = d0v + jj;                                                  \
      (VL)[d * 32 + ((kb ^ (d & 15)) << 1) + kl] =                             \
          ((unsigned int)(unsigned short)v0[jj]) |                             \
          (((unsigned int)(unsigned short)v1[jj]) << 16);                      \
    }                                                                          \
    kgp += ADV; vgp += ADV;                                                    \
  } while (0)

// compute one 64-kv tile from (KL, VL) — byte-identical to r6's body
#define ATILE(KL, VL) do {                                                     \
    f32x4 sacc[4][2] = {};                                                     \
    _Pragma("unroll")                                                          \
    for (int kh = 0; kh < 2; ++kh) {                                           \
      short8 kf[4];                                                            \
      _Pragma("unroll")                                                        \
      for (int ct = 0; ct < 4; ++ct)                                           \
        kf[ct] = *(const short8*)&(KL)[(ct * 16 + l15) * 72 + kh * 32 + quad * 8]; \
      __builtin_amdgcn_s_setprio(1);                                           \
      _Pragma("unroll")                                                        \
      for (int ct = 0; ct < 4; ++ct)                                           \
        _Pragma("unroll")                                                      \
        for (int rt = 0; rt < 2; ++rt)                                         \
          sacc[ct][rt] = __builtin_amdgcn_mfma_f32_16x16x32_bf16(              \
              kf[ct], qf[rt][kh], sacc[ct][rt], 0, 0, 0);                      \
      __builtin_amdgcn_s_setprio(0);                                           \
    }                                                                          \
    sv4 p16[4][2];                                                             \
    _Pragma("unroll")                                                          \
    for (int rt = 0; rt < 2; ++rt) {                                           \
      float rs = 0.f;                                                          \
      _Pragma("unroll")                                                        \
      for (int ct = 0; ct < 4; ++ct) {                                         \
        float p0 = __builtin_amdgcn_exp2f(sacc[ct][rt][0]);                    \
        float p1 = __builtin_amdgcn_exp2f(sacc[ct][rt][1]);                    \
        float p2 = __builtin_amdgcn_exp2f(sacc[ct][rt][2]);                    \
        float p3 = __builtin_amdgcn_exp2f(sacc[ct][rt][3]);                    \
        rs += (p0 + p1) + (p2 + p3);                                           \
        u32x2 pw;                                                              \
        pw[0] = pk_bf16(p0, p1);                                               \
        pw[1] = pk_bf16(p2, p3);                                               \
        p16[ct][rt] = __builtin_bit_cast(sv4, pw);                             \
      }                                                                        \
      rs += __shfl_xor(rs, 16, 64);                                            \
      rs += __shfl_xor(rs, 32, 64);                                            \
      lrow[rt] += rs;                                                          \
    }                                                                          \
    __builtin_amdgcn_s_setprio(1);                                             \
    _Pragma("unroll")                                                          \
    for (int ct = 0; ct < 4; ++ct) {                                           \
      _Pragma("unroll")                                                        \
      for (int dt = 0; dt < 4; ++dt) {                                         \
        const int d = dt * 16 + l15;                                           \
        const int idx = d * 32 + (((ct * 4 + quad) ^ (d & 15)) << 1);          \
        const sv4 vfr = *(const sv4*)&(VL)[idx];                               \
        _Pragma("unroll")                                                      \
        for (int rt = 0; rt < 2; ++rt)                                         \
          oaccT[dt][rt] = mfma_16x16x16_bf16(vfr, p16[ct][rt], oaccT[dt][rt]); \
      }                                                                        \
    }                                                                          \
    __builtin_amdgcn_s_setprio(0);                                             \
  } while (0)

__global__ __launch_bounds__(512, 4)
void attn_s(const u16* __restrict__ QKV, u16* __restrict__ O)
{
  __shared__ __align__(16) u16 Ka[64 * 72], Kb[64 * 72];          // 9KB each
  __shared__ __align__(16) unsigned int Va[64 * 32], Vb[64 * 32]; // 8KB each
  const int tid  = threadIdx.x;
  const int wave = tid >> 6, lane = tid & 63;
  const int quad = lane >> 4, l15 = lane & 15;

  // XCD-panel swizzle: all 8 qt of a panel -> same XCD, consecutive slots.
  const int i  = blockIdx.x;
  const int j  = i >> 3;
  const int qt = j & 7;
  const int g  = (i & 7) + ((j >> 3) << 3);      // panel id = h + 16*z
  const int h  = g & 15;
  const int z  = g >> 4;

  const u16* QKVb = QKV + (size_t)z * 2048 * 3072;
  u16* Ob = O + (size_t)z * 2048 * 1024;
  const int q0 = qt * 256;

  // Q fragments (B-operand of x32: n=l15 -> q, k=quad*8+jj -> d)
  short8 qf[2][2];
  const u16* Qb = QKVb + (size_t)(q0 + wave * 32) * 3072 + h * 64;
#pragma unroll
  for (int rt = 0; rt < 2; ++rt)
#pragma unroll
    for (int kh = 0; kh < 2; ++kh)
      qf[rt][kh] = *(const short8*)(Qb + (size_t)(rt * 16 + l15) * 3072 + kh * 32 + quad * 8);

  f32x4 oaccT[4][2] = {};    // [dt][rt]: C[m=d_local][n=q]
  float lrow[2] = {};

  // staging ids — all 512 threads:
  //  K: row = tid>>3 (0..63), 16B chunk = tid&7; LDS [row][72] (r6 layout)
  //  V: pair p = tid&31 (kv rows 2p,2p+1), d-group d0v = (tid>>5)*4 (r8 split)
  const int kwoff = (tid >> 3) * 72 + (tid & 7) * 8;
  const int d0v = (tid >> 5) * 4;
  const int kb  = (tid >> 1) & 15;     // p>>1
  const int kl  = tid & 1;             // p&1

  const u16* kgp = QKVb + 1024 + h * 64 + (size_t)(tid >> 3) * 3072 + (tid & 7) * 8;
  const u16* vgp = QKVb + 2048 + h * 64 + (size_t)(2 * (tid & 31)) * 3072 + d0v;
  const size_t ADV = (size_t)64 * 3072;

  STAGE(Ka, Va);               // tile 0
  __syncthreads();             // buf A visible
#pragma unroll 1
  for (int itp = 0; itp < 16; ++itp) {
    STAGE(Kb, Vb);             // tile 2*itp+1 (B readers finished last iter)
    ATILE(Ka, Va);             // tile 2*itp
    __syncthreads();           // B staged; all done reading A
    if (itp != 15) STAGE(Ka, Va);  // tile 2*itp+2
    ATILE(Kb, Vb);             // tile 2*itp+1
    __syncthreads();           // A staged; all done reading B
  }

  // store O[q][d]: q = q0+wave*32+rt*16+l15 (col), d = dt*16+quad*4+r (row)
#pragma unroll
  for (int rt = 0; rt < 2; ++rt) {
    const float inv = 1.f / lrow[rt];
    u16* Op = Ob + (size_t)(q0 + wave * 32 + rt * 16 + l15) * 1024 + h * 64;
#pragma unroll
    for (int dt = 0; dt < 4; ++dt) {
      u32x2 ow;
      ow[0] = pk_bf16(oaccT[dt][rt][0] * inv, oaccT[dt][rt][1] * inv);
      ow[1] = pk_bf16(oaccT[dt][rt][2] * inv, oaccT[dt][rt][3] * inv);
      *(sv4*)(Op + dt * 16 + quad * 4) = __builtin_bit_cast(sv4, ow);
    }
  }
}

// ---------------------------------------------------------------------------
extern "C" void kernel_launch(void* const* d_in, const int* in_sizes, int n_in,
                              void* d_out, int out_size, void* d_ws, size_t ws_size,
                              hipStream_t stream)
{
  // Common: flag + converted weights.
  int* flag = (int*)d_ws;
  u16* Wc   = (u16*)((char*)d_ws + 256);
  u16* bc   = Wc + (size_t)4 * 1048576;           // 4M u16
  char* after_wb = (char*)(bc + 4096);

  detect_dtype<<<1, 64, 0, stream>>>((const u16*)d_in[0], flag);
  convert_wb<<<2050, 256, 0, stream>>>(d_in[1], d_in[3], d_in[5], d_in[7],
                                       d_in[2], d_in[4], d_in[6], d_in[8],
                                       Wc, bc, flag);

  const size_t need_batched =
      (size_t)(after_wb - (char*)d_ws) + ((size_t)8192 * 3072 + (size_t)8192 * 1024) * 2;

  if (ws_size >= need_batched) {
    // ---- batched path: one launch per stage, full-device grids ----
    u16* QKV = (u16*)after_wb;
    u16* xO  = QKV + (size_t)8192 * 3072;   // xc before QKV-GEMM; O after attn

    convert_x_off<<<4096, 256, 0, stream>>>(d_in[0], xO, flag, 0);
    gemm_bt<<<dim3(64, 24), 256, 0, stream>>>(xO, Wc, Wc + 1048576, Wc + 2097152,
                                              bc, QKV, 3072, 1024);
    attn_s<<<512, 512, 0, stream>>>(QKV, xO);
    gemm_bt_out<<<dim3(64, 8), 256, 0, stream>>>(xO, Wc + (size_t)3 * 1048576,
                                                 bc + 3 * 1024, d_out, d_out,
                                                 1024, 1024, flag);
  } else {
    // ---- fallback: per-batch path (ws ~29.4 MB, proven) ----
    u16* xc   = (u16*)after_wb;
    u16* QKVb = xc + (size_t)2048 * 1024;
    u16* Obb  = QKVb + (size_t)2048 * 3072;
    for (int b = 0; b < 4; ++b) {
      convert_x_off<<<1024, 256, 0, stream>>>(d_in[0], xc, flag, b);
      gemm_bt<<<dim3(16, 24), 256, 0, stream>>>(xc, Wc, Wc + 1048576, Wc + 2097152,
                                                bc, QKVb, 3072, 1024);
      attn_s<<<128, 512, 0, stream>>>(QKVb, Obb);
      void* outb16 = (void*)((char*)d_out + (size_t)b * 2048 * 1024 * 2);
      void* outb32 = (void*)((char*)d_out + (size_t)b * 2048 * 1024 * 4);
      gemm_bt_out<<<dim3(16, 8), 256, 0, stream>>>(Obb, Wc + (size_t)3 * 1048576,
                                                   bc + 3 * 1024, outb16, outb32,
                                                   1024, 1024, flag);
    }
  }
}

// Round 12
// 305.032 us; speedup vs baseline: 1.2477x; 1.0727x over previous
//
#include <hip/hip_runtime.h>
#include <cstdint>
#include <cstddef>

typedef unsigned short u16;
typedef __attribute__((ext_vector_type(8))) short short8;
typedef __attribute__((ext_vector_type(4))) short sv4;    // 4 bf16 frag
typedef __attribute__((ext_vector_type(4))) float f32x4;
typedef __attribute__((ext_vector_type(2))) unsigned int u32x2;
typedef __attribute__((ext_vector_type(4))) unsigned int u32x4;

__device__ __forceinline__ u16 f2bf(float f) {
  unsigned int u = __builtin_bit_cast(unsigned int, f);
  u += 0x7FFFu + ((u >> 16) & 1u);
  return (u16)(u >> 16);
}
__device__ __forceinline__ float bf2f(u16 v) {
  return __builtin_bit_cast(float, ((unsigned int)v) << 16);
}

// packed f32x2 -> bf16x2 (RNE). gfx950 has v_cvt_pk_bf16_f32; guard builtin
// probe with __HIP_DEVICE_COMPILE__ (host pass reports no amdgcn builtins, r7).
__device__ __forceinline__ unsigned int pk_bf16(float a, float b) {
#if defined(__HIP_DEVICE_COMPILE__) && __has_builtin(__builtin_amdgcn_cvt_pk_bf16_f32)
  typedef __attribute__((ext_vector_type(2))) __bf16 bf16x2;
  bf16x2 r = __builtin_amdgcn_cvt_pk_bf16_f32(a, b);
  return __builtin_bit_cast(unsigned int, r);
#else
  return (unsigned int)f2bf(a) | ((unsigned int)f2bf(b) << 16);
#endif
}

// 16x16x16 bf16 MFMA (device-gated probe — r7 lesson).
__device__ __forceinline__ f32x4 mfma_16x16x16_bf16(sv4 a, sv4 b, f32x4 c) {
#if defined(__HIP_DEVICE_COMPILE__)
#if __has_builtin(__builtin_amdgcn_mfma_f32_16x16x16bf16_1k)
  return __builtin_amdgcn_mfma_f32_16x16x16bf16_1k(a, b, c, 0, 0, 0);
#elif __has_builtin(__builtin_amdgcn_mfma_f32_16x16x16_bf16)
  return __builtin_amdgcn_mfma_f32_16x16x16_bf16(a, b, c, 0, 0, 0);
#else
  asm volatile("v_mfma_f32_16x16x16_bf16 %0, %1, %2, %0\n\ts_nop 7\n\ts_nop 4"
               : "+v"(c) : "v"(a), "v"(b));
  return c;
#endif
#else
  (void)a; (void)b;
  return c;   // host stub, never executed
#endif
}

// async global->LDS, 16B per lane; LDS dest = wave-uniform base + lane*16
// (used by the GEMMs, where it is proven fast on this harness)
#define GLD_LDS(g, l) __builtin_amdgcn_global_load_lds( \
    (const __attribute__((address_space(1))) void*)(g), \
    (__attribute__((address_space(3))) void*)(l), 16, 0, 0)

// (1/8) * log2(e): folded into Wq/bq at convert time so attn's exp2 needs no mul
#define QSCL 0.18033688011112042f

// ---------------------------------------------------------------------------
// dtype probe: flag 1 = fp32 inputs (established on this harness), 0 = bf16.
// ---------------------------------------------------------------------------
__global__ void detect_dtype(const u16* __restrict__ x, int* __restrict__ flag)
{
  const int lane = threadIdx.x;          // 64 threads
  int hit = 0;
#pragma unroll
  for (int j = 0; j < 4; ++j) {
    float v = bf2f(x[lane * 4 + j]);
    if (!(v > -1000.f && v < 1000.f)) hit = 1;
  }
  unsigned long long any = __ballot(hit != 0);
  if (lane == 0) *flag = (any != 0ull) ? 1 : 0;
}

// ---------------------------------------------------------------------------
// Convert weights+biases to bf16: Wc=[Wq|Wk|Wv|Wo], bc=[bq|bk|bv|bo].
// Wq and bq are pre-scaled by QSCL (softmax scale fold).
// ---------------------------------------------------------------------------
__global__ __launch_bounds__(256)
void convert_wb(const void* Wq, const void* Wk, const void* Wv, const void* Wo,
                const void* bq, const void* bk, const void* bv, const void* bo,
                u16* __restrict__ Wc, u16* __restrict__ bc, const int* __restrict__ flag)
{
  const int fp32 = *flag;
  const size_t base = ((size_t)blockIdx.x * 256 + threadIdx.x) * 8;
  const void* src; u16* dst; size_t local; int sel;
  if (base < (size_t)4 * 1048576) {
    sel = (int)(base >> 20);
    local = base & 1048575u;
    src = (sel == 0) ? Wq : (sel == 1) ? Wk : (sel == 2) ? Wv : Wo;
    dst = Wc + (size_t)sel * 1048576 + local;
  } else {
    const size_t rem = base - (size_t)4 * 1048576;   // 0..4095
    sel = (int)(rem >> 10);
    local = rem & 1023u;
    src = (sel == 0) ? bq : (sel == 1) ? bk : (sel == 2) ? bv : bo;
    dst = bc + (size_t)sel * 1024 + local;
  }
  const float scale = (sel == 0) ? QSCL : 1.0f;
  if (fp32) {
    const float* s = (const float*)src + local;
    u32x4 w;
#pragma unroll
    for (int j = 0; j < 4; ++j) w[j] = pk_bf16(s[2 * j] * scale, s[2 * j + 1] * scale);
    *(short8*)dst = __builtin_bit_cast(short8, w);
  } else {
    const u16* s = (const u16*)src + local;
    if (sel == 0) {
      u32x4 w;
#pragma unroll
      for (int j = 0; j < 4; ++j)
        w[j] = pk_bf16(bf2f(s[2 * j]) * scale, bf2f(s[2 * j + 1]) * scale);
      *(short8*)dst = __builtin_bit_cast(short8, w);
    } else {
      *(short8*)dst = *(const short8*)s;
    }
  }
}

// x convert: grid*256*8 elements from src element offset b*2097152; dst from 0.
__global__ __launch_bounds__(256)
void convert_x_off(const void* __restrict__ x, u16* __restrict__ dst,
                   const int* __restrict__ flag, int b)
{
  const int fp32 = *flag;
  const size_t base = ((size_t)blockIdx.x * 256 + threadIdx.x) * 8;
  const size_t src_e = (size_t)b * 2048 * 1024 + base;
  if (fp32) {
    const float* s = (const float*)x + src_e;
    u32x4 w;
#pragma unroll
    for (int j = 0; j < 4; ++j) w[j] = pk_bf16(s[2 * j], s[2 * j + 1]);
    *(short8*)(dst + base) = __builtin_bit_cast(short8, w);
  } else {
    *(short8*)(dst + base) = *(const short8*)((const u16*)x + src_e);
  }
}

// ---------------------------------------------------------------------------
// GEMM (bf16 in/out): C[m,n] = sum_k A[m,k]*B[n,k] + bias[sel*1024 + n%1024].
// 128x128 tile, BK=32, 4 waves each 64x64 (m97 structure).
// r9: blockIdx.x = m-tile (fast) so concurrent blocks share one B panel in L2.
// ---------------------------------------------------------------------------
__global__ __launch_bounds__(256)
void gemm_bt(const u16* __restrict__ A,
             const u16* __restrict__ B0, const u16* __restrict__ B1, const u16* __restrict__ B2,
             const u16* __restrict__ bias, u16* __restrict__ C, int Ntot, int K)
{
  __shared__ __align__(16) u16 Alds[128 * 32];
  __shared__ __align__(16) u16 Blds[128 * 32];
  const int tid  = threadIdx.x;
  const int wave = tid >> 6, lane = tid & 63;
  const int quad = lane >> 4, l15 = lane & 15;
  const int m0  = blockIdx.x * 128;        // m fast-varying (L2 B-panel reuse)
  const int n0g = blockIdx.y * 128;
  const int sel = n0g >> 10;
  const u16* Bm = (sel == 0) ? B0 : ((sel == 1) ? B1 : B2);
  const u16* bb = bias + (size_t)sel * 1024;
  const int n0 = n0g & 1023;
  const int wr = (wave >> 1) * 64, wc = (wave & 1) * 64;

  f32x4 acc[4][4] = {};
  const int srow = lane >> 2;        // 0..15
  const int skc  = (lane & 3) * 8;   // 16B k-chunk
  const u16* Ag = A  + (size_t)(m0 + srow) * K + skc;
  const u16* Bg = Bm + (size_t)(n0 + srow) * K + skc;

  for (int kt = 0; kt < K; kt += 32) {
    __syncthreads();
#pragma unroll
    for (int t = 0; t < 2; ++t) {
      const int seg = wave * 2 + t;
      GLD_LDS(Ag + (size_t)(seg * 16) * K + kt, Alds + seg * 512);
      GLD_LDS(Bg + (size_t)(seg * 16) * K + kt, Blds + seg * 512);
    }
    __syncthreads();

    short8 af[4], bfr[4];
#pragma unroll
    for (int i = 0; i < 4; ++i)
      af[i] = *(const short8*)&Alds[(wr + i * 16 + l15) * 32 + quad * 8];
#pragma unroll
    for (int j = 0; j < 4; ++j)
      bfr[j] = *(const short8*)&Blds[(wc + j * 16 + l15) * 32 + quad * 8];
#pragma unroll
    for (int i = 0; i < 4; ++i)
#pragma unroll
      for (int j = 0; j < 4; ++j)
        acc[i][j] = __builtin_amdgcn_mfma_f32_16x16x32_bf16(af[i], bfr[j], acc[i][j], 0, 0, 0);
  }

#pragma unroll
  for (int i = 0; i < 4; ++i) {
    const int mr = m0 + wr + i * 16 + quad * 4;
#pragma unroll
    for (int j = 0; j < 4; ++j) {
      const int ncl = wc + j * 16 + l15;
      const float bvv = bf2f(bb[n0 + ncl]);
#pragma unroll
      for (int r = 0; r < 4; ++r)
        C[(size_t)(mr + r) * Ntot + n0g + ncl] = f2bf(acc[i][j][r] + bvv);
    }
  }
}

// ---------------------------------------------------------------------------
// Out-proj GEMM: writes d_out in dtype chosen by *flag. m-tile fast (r9).
// ---------------------------------------------------------------------------
__global__ __launch_bounds__(256)
void gemm_bt_out(const u16* __restrict__ A, const u16* __restrict__ Bm,
                 const u16* __restrict__ bias, void* __restrict__ C16,
                 void* __restrict__ C32, int Ntot, int K, const int* __restrict__ flag)
{
  __shared__ __align__(16) u16 Alds[128 * 32];
  __shared__ __align__(16) u16 Blds[128 * 32];
  const int tid  = threadIdx.x;
  const int wave = tid >> 6, lane = tid & 63;
  const int quad = lane >> 4, l15 = lane & 15;
  const int m0 = blockIdx.x * 128;
  const int n0 = blockIdx.y * 128;
  const int wr = (wave >> 1) * 64, wc = (wave & 1) * 64;

  f32x4 acc[4][4] = {};
  const int srow = lane >> 2;
  const int skc  = (lane & 3) * 8;
  const u16* Ag = A  + (size_t)(m0 + srow) * K + skc;
  const u16* Bg = Bm + (size_t)(n0 + srow) * K + skc;

  for (int kt = 0; kt < K; kt += 32) {
    __syncthreads();
#pragma unroll
    for (int t = 0; t < 2; ++t) {
      const int seg = wave * 2 + t;
      GLD_LDS(Ag + (size_t)(seg * 16) * K + kt, Alds + seg * 512);
      GLD_LDS(Bg + (size_t)(seg * 16) * K + kt, Blds + seg * 512);
    }
    __syncthreads();

    short8 af[4], bfr[4];
#pragma unroll
    for (int i = 0; i < 4; ++i)
      af[i] = *(const short8*)&Alds[(wr + i * 16 + l15) * 32 + quad * 8];
#pragma unroll
    for (int j = 0; j < 4; ++j)
      bfr[j] = *(const short8*)&Blds[(wc + j * 16 + l15) * 32 + quad * 8];
#pragma unroll
    for (int i = 0; i < 4; ++i)
#pragma unroll
      for (int j = 0; j < 4; ++j)
        acc[i][j] = __builtin_amdgcn_mfma_f32_16x16x32_bf16(af[i], bfr[j], acc[i][j], 0, 0, 0);
  }

  if (*flag != 0) {
    float* Cf = (float*)C32;
#pragma unroll
    for (int i = 0; i < 4; ++i) {
      const int mr = m0 + wr + i * 16 + quad * 4;
#pragma unroll
      for (int j = 0; j < 4; ++j) {
        const int ncl = wc + j * 16 + l15;
        const float bvv = bf2f(bias[n0 + ncl]);
#pragma unroll
        for (int r = 0; r < 4; ++r)
          Cf[(size_t)(mr + r) * Ntot + n0 + ncl] = acc[i][j][r] + bvv;
      }
    }
  } else {
    u16* Cb = (u16*)C16;
#pragma unroll
    for (int i = 0; i < 4; ++i) {
      const int mr = m0 + wr + i * 16 + quad * 4;
#pragma unroll
      for (int j = 0; j < 4; ++j) {
        const int ncl = wc + j * 16 + l15;
        const float bvv = bf2f(bias[n0 + ncl]);
#pragma unroll
        for (int r = 0; r < 4; ++r)
          Cb[(size_t)(mr + r) * Ntot + n0 + ncl] = f2bf(acc[i][j][r] + bvv);
      }
    }
  }
}

// ---------------------------------------------------------------------------
// Flash attention, S^T formulation (register-resident P). Q pre-scaled by
// QSCL at the projection, so exp2 applies directly to sacc.
//
// r11 post-mortem: double-buffer (STAGE before ATILE, no barrier between)
// let the compiler extend staged-value lifetimes into the MFMA region ->
// partial spill (WRITE 16->39MB), Mfma 36.7->29.6, dur 118.7->145us.
// Double-buffer lever CLOSED (3 failed variants: r5, r7, r11).
//
// r12 = r6's proven schedule VERBATIM ({bar; stage; bar; compute} — barrier
// between stage and compute kills value-lifetime extension; r6 had zero
// spill) with ONE delta: staging spread over all 512 threads using r11's
// correctness-proven mapping (1x16B K chunk + 1 V pair-pack per thread;
// r11 passed with absmax identical to r6). Per-thread staging work halves.
// Tripwires: WRITE >> 20MB or FETCH >> 40MB => revert to pure r6.
// ---------------------------------------------------------------------------
__global__ __launch_bounds__(512, 4)
void attn_s(const u16* __restrict__ QKV, u16* __restrict__ O)
{
  __shared__ __align__(16) u16 Klds[64 * 72];          // [kv][d], padded
  __shared__ __align__(16) unsigned int Vlds[64 * 32]; // V^T pairs, swizzled
  const int tid  = threadIdx.x;
  const int wave = tid >> 6, lane = tid & 63;
  const int quad = lane >> 4, l15 = lane & 15;

  // XCD-panel swizzle: all 8 qt of a panel -> same XCD, consecutive slots.
  const int i  = blockIdx.x;
  const int j  = i >> 3;
  const int qt = j & 7;
  const int g  = (i & 7) + ((j >> 3) << 3);      // panel id = h + 16*z
  const int h  = g & 15;
  const int z  = g >> 4;

  const u16* QKVb = QKV + (size_t)z * 2048 * 3072;
  u16* Ob = O + (size_t)z * 2048 * 1024;
  const int q0 = qt * 256;

  // Q fragments (B-operand of x32: n=l15 -> q, k=quad*8+jj -> d)
  short8 qf[2][2];
  const u16* Qb = QKVb + (size_t)(q0 + wave * 32) * 3072 + h * 64;
#pragma unroll
  for (int rt = 0; rt < 2; ++rt)
#pragma unroll
    for (int kh = 0; kh < 2; ++kh)
      qf[rt][kh] = *(const short8*)(Qb + (size_t)(rt * 16 + l15) * 3072 + kh * 32 + quad * 8);

  f32x4 oaccT[4][2] = {};    // [dt][rt]: C[m=d_local][n=q]
  float lrow[2] = {};

  // staging ids — all 512 threads (r11-proven mapping):
  //  K: row = tid>>3 (0..63), 16B chunk = tid&7; LDS [row][72]
  //  V: pair p = tid&31 (kv rows 2p,2p+1), d-group d0v = (tid>>5)*4
  const int kwoff = (tid >> 3) * 72 + (tid & 7) * 8;
  const int d0v = (tid >> 5) * 4;
  const int kb  = (tid >> 1) & 15;     // p>>1
  const int kl  = tid & 1;             // p&1

  const u16* kgp = QKVb + 1024 + h * 64 + (size_t)(tid >> 3) * 3072 + (tid & 7) * 8;
  const u16* vgp = QKVb + 2048 + h * 64 + (size_t)(2 * (tid & 31)) * 3072 + d0v;
  const size_t ADV = (size_t)64 * 3072;

  for (int kv0 = 0; kv0 < 2048; kv0 += 64) {
    __syncthreads();
    {
      *(short8*)&Klds[kwoff] = *(const short8*)kgp;
      const sv4 v0 = *(const sv4*)vgp;
      const sv4 v1 = *(const sv4*)(vgp + 3072);
#pragma unroll
      for (int jj = 0; jj < 4; ++jj) {
        const int d = d0v + jj;
        Vlds[d * 32 + ((kb ^ (d & 15)) << 1) + kl] =
            ((unsigned int)(unsigned short)v0[jj]) |
            (((unsigned int)(unsigned short)v1[jj]) << 16);
      }
      kgp += ADV; vgp += ADV;
    }
    __syncthreads();

    // S^T tiles: sacc[ct][rt], kv_local = ct*16 + quad*4 + r, q = rt*16 + l15
    f32x4 sacc[4][2] = {};
#pragma unroll
    for (int kh = 0; kh < 2; ++kh) {
      short8 kf[4];
#pragma unroll
      for (int ct = 0; ct < 4; ++ct)
        kf[ct] = *(const short8*)&Klds[(ct * 16 + l15) * 72 + kh * 32 + quad * 8];
      __builtin_amdgcn_s_setprio(1);
#pragma unroll
      for (int ct = 0; ct < 4; ++ct)
#pragma unroll
        for (int rt = 0; rt < 2; ++rt)
          sacc[ct][rt] = __builtin_amdgcn_mfma_f32_16x16x32_bf16(kf[ct], qf[rt][kh], sacc[ct][rt], 0, 0, 0);
      __builtin_amdgcn_s_setprio(0);
    }

    // softmax (max-free; Q pre-scaled) + pack P^T B-frags in registers
    sv4 p16[4][2];
#pragma unroll
    for (int rt = 0; rt < 2; ++rt) {
      float rs = 0.f;
#pragma unroll
      for (int ct = 0; ct < 4; ++ct) {
        float p0 = __builtin_amdgcn_exp2f(sacc[ct][rt][0]);
        float p1 = __builtin_amdgcn_exp2f(sacc[ct][rt][1]);
        float p2 = __builtin_amdgcn_exp2f(sacc[ct][rt][2]);
        float p3 = __builtin_amdgcn_exp2f(sacc[ct][rt][3]);
        rs += (p0 + p1) + (p2 + p3);
        u32x2 pw;
        pw[0] = pk_bf16(p0, p1);
        pw[1] = pk_bf16(p2, p3);
        p16[ct][rt] = __builtin_bit_cast(sv4, pw);
      }
      rs += __shfl_xor(rs, 16, 64);
      rs += __shfl_xor(rs, 32, 64);
      lrow[rt] += rs;
    }

    // PV: O^T += V^T * P^T, 16x16x16 per (dt, ct, rt)
    __builtin_amdgcn_s_setprio(1);
#pragma unroll
    for (int ct = 0; ct < 4; ++ct) {
#pragma unroll
      for (int dt = 0; dt < 4; ++dt) {
        const int d = dt * 16 + l15;
        const int idx = d * 32 + (((ct * 4 + quad) ^ (d & 15)) << 1);
        const sv4 vfr = *(const sv4*)&Vlds[idx];   // kv = ct*16+quad*4 .. +3
#pragma unroll
        for (int rt = 0; rt < 2; ++rt)
          oaccT[dt][rt] = mfma_16x16x16_bf16(vfr, p16[ct][rt], oaccT[dt][rt]);
      }
    }
    __builtin_amdgcn_s_setprio(0);
  }

  // store O[q][d]: q = q0+wave*32+rt*16+l15 (col), d = dt*16+quad*4+r (row)
#pragma unroll
  for (int rt = 0; rt < 2; ++rt) {
    const float inv = 1.f / lrow[rt];
    u16* Op = Ob + (size_t)(q0 + wave * 32 + rt * 16 + l15) * 1024 + h * 64;
#pragma unroll
    for (int dt = 0; dt < 4; ++dt) {
      u32x2 ow;
      ow[0] = pk_bf16(oaccT[dt][rt][0] * inv, oaccT[dt][rt][1] * inv);
      ow[1] = pk_bf16(oaccT[dt][rt][2] * inv, oaccT[dt][rt][3] * inv);
      *(sv4*)(Op + dt * 16 + quad * 4) = __builtin_bit_cast(sv4, ow);
    }
  }
}

// ---------------------------------------------------------------------------
extern "C" void kernel_launch(void* const* d_in, const int* in_sizes, int n_in,
                              void* d_out, int out_size, void* d_ws, size_t ws_size,
                              hipStream_t stream)
{
  // Common: flag + converted weights.
  int* flag = (int*)d_ws;
  u16* Wc   = (u16*)((char*)d_ws + 256);
  u16* bc   = Wc + (size_t)4 * 1048576;           // 4M u16
  char* after_wb = (char*)(bc + 4096);

  detect_dtype<<<1, 64, 0, stream>>>((const u16*)d_in[0], flag);
  convert_wb<<<2050, 256, 0, stream>>>(d_in[1], d_in[3], d_in[5], d_in[7],
                                       d_in[2], d_in[4], d_in[6], d_in[8],
                                       Wc, bc, flag);

  const size_t need_batched =
      (size_t)(after_wb - (char*)d_ws) + ((size_t)8192 * 3072 + (size_t)8192 * 1024) * 2;

  if (ws_size >= need_batched) {
    // ---- batched path: one launch per stage, full-device grids ----
    u16* QKV = (u16*)after_wb;
    u16* xO  = QKV + (size_t)8192 * 3072;   // xc before QKV-GEMM; O after attn

    convert_x_off<<<4096, 256, 0, stream>>>(d_in[0], xO, flag, 0);
    gemm_bt<<<dim3(64, 24), 256, 0, stream>>>(xO, Wc, Wc + 1048576, Wc + 2097152,
                                              bc, QKV, 3072, 1024);
    attn_s<<<512, 512, 0, stream>>>(QKV, xO);
    gemm_bt_out<<<dim3(64, 8), 256, 0, stream>>>(xO, Wc + (size_t)3 * 1048576,
                                                 bc + 3 * 1024, d_out, d_out,
                                                 1024, 1024, flag);
  } else {
    // ---- fallback: per-batch path (ws ~29.4 MB, proven) ----
    u16* xc   = (u16*)after_wb;
    u16* QKVb = xc + (size_t)2048 * 1024;
    u16* Obb  = QKVb + (size_t)2048 * 3072;
    for (int b = 0; b < 4; ++b) {
      convert_x_off<<<1024, 256, 0, stream>>>(d_in[0], xc, flag, b);
      gemm_bt<<<dim3(16, 24), 256, 0, stream>>>(xc, Wc, Wc + 1048576, Wc + 2097152,
                                                bc, QKVb, 3072, 1024);
      attn_s<<<128, 512, 0, stream>>>(QKVb, Obb);
      void* outb16 = (void*)((char*)d_out + (size_t)b * 2048 * 1024 * 2);
      void* outb32 = (void*)((char*)d_out + (size_t)b * 2048 * 1024 * 4);
      gemm_bt_out<<<dim3(16, 8), 256, 0, stream>>>(Obb, Wc + (size_t)3 * 1048576,
                                                   bc + 3 * 1024, outb16, outb32,
                                                   1024, 1024, flag);
    }
  }
}

// Round 13
// 302.552 us; speedup vs baseline: 1.2579x; 1.0082x over previous
//
#include <hip/hip_runtime.h>
#include <cstdint>
#include <cstddef>

typedef unsigned short u16;
typedef __attribute__((ext_vector_type(8))) short short8;
typedef __attribute__((ext_vector_type(4))) short sv4;    // 4 bf16 frag
typedef __attribute__((ext_vector_type(4))) float f32x4;
typedef __attribute__((ext_vector_type(2))) unsigned int u32x2;
typedef __attribute__((ext_vector_type(4))) unsigned int u32x4;

__device__ __forceinline__ u16 f2bf(float f) {
  unsigned int u = __builtin_bit_cast(unsigned int, f);
  u += 0x7FFFu + ((u >> 16) & 1u);
  return (u16)(u >> 16);
}
__device__ __forceinline__ float bf2f(u16 v) {
  return __builtin_bit_cast(float, ((unsigned int)v) << 16);
}

// packed f32x2 -> bf16x2 (RNE). gfx950 has v_cvt_pk_bf16_f32; guard builtin
// probe with __HIP_DEVICE_COMPILE__ (host pass reports no amdgcn builtins, r7).
__device__ __forceinline__ unsigned int pk_bf16(float a, float b) {
#if defined(__HIP_DEVICE_COMPILE__) && __has_builtin(__builtin_amdgcn_cvt_pk_bf16_f32)
  typedef __attribute__((ext_vector_type(2))) __bf16 bf16x2;
  bf16x2 r = __builtin_amdgcn_cvt_pk_bf16_f32(a, b);
  return __builtin_bit_cast(unsigned int, r);
#else
  return (unsigned int)f2bf(a) | ((unsigned int)f2bf(b) << 16);
#endif
}

// 16x16x16 bf16 MFMA (device-gated probe — r7 lesson).
__device__ __forceinline__ f32x4 mfma_16x16x16_bf16(sv4 a, sv4 b, f32x4 c) {
#if defined(__HIP_DEVICE_COMPILE__)
#if __has_builtin(__builtin_amdgcn_mfma_f32_16x16x16bf16_1k)
  return __builtin_amdgcn_mfma_f32_16x16x16bf16_1k(a, b, c, 0, 0, 0);
#elif __has_builtin(__builtin_amdgcn_mfma_f32_16x16x16_bf16)
  return __builtin_amdgcn_mfma_f32_16x16x16_bf16(a, b, c, 0, 0, 0);
#else
  asm volatile("v_mfma_f32_16x16x16_bf16 %0, %1, %2, %0\n\ts_nop 7\n\ts_nop 4"
               : "+v"(c) : "v"(a), "v"(b));
  return c;
#endif
#else
  (void)a; (void)b;
  return c;   // host stub, never executed
#endif
}

// async global->LDS, 16B per lane; LDS dest = wave-uniform base + lane*16
// (used by the GEMMs, where it is proven fast on this harness)
#define GLD_LDS(g, l) __builtin_amdgcn_global_load_lds( \
    (const __attribute__((address_space(1))) void*)(g), \
    (__attribute__((address_space(3))) void*)(l), 16, 0, 0)

// (1/8) * log2(e): folded into Wq/bq at convert time so attn's exp2 needs no mul
#define QSCL 0.18033688011112042f

// ---------------------------------------------------------------------------
// dtype probe: flag 1 = fp32 inputs (established on this harness), 0 = bf16.
// ---------------------------------------------------------------------------
__global__ void detect_dtype(const u16* __restrict__ x, int* __restrict__ flag)
{
  const int lane = threadIdx.x;          // 64 threads
  int hit = 0;
#pragma unroll
  for (int j = 0; j < 4; ++j) {
    float v = bf2f(x[lane * 4 + j]);
    if (!(v > -1000.f && v < 1000.f)) hit = 1;
  }
  unsigned long long any = __ballot(hit != 0);
  if (lane == 0) *flag = (any != 0ull) ? 1 : 0;
}

// ---------------------------------------------------------------------------
// Convert weights+biases to bf16: Wc=[Wq|Wk|Wv|Wo], bc=[bq|bk|bv|bo].
// Wq and bq are pre-scaled by QSCL (softmax scale fold).
// ---------------------------------------------------------------------------
__global__ __launch_bounds__(256)
void convert_wb(const void* Wq, const void* Wk, const void* Wv, const void* Wo,
                const void* bq, const void* bk, const void* bv, const void* bo,
                u16* __restrict__ Wc, u16* __restrict__ bc, const int* __restrict__ flag)
{
  const int fp32 = *flag;
  const size_t base = ((size_t)blockIdx.x * 256 + threadIdx.x) * 8;
  const void* src; u16* dst; size_t local; int sel;
  if (base < (size_t)4 * 1048576) {
    sel = (int)(base >> 20);
    local = base & 1048575u;
    src = (sel == 0) ? Wq : (sel == 1) ? Wk : (sel == 2) ? Wv : Wo;
    dst = Wc + (size_t)sel * 1048576 + local;
  } else {
    const size_t rem = base - (size_t)4 * 1048576;   // 0..4095
    sel = (int)(rem >> 10);
    local = rem & 1023u;
    src = (sel == 0) ? bq : (sel == 1) ? bk : (sel == 2) ? bv : bo;
    dst = bc + (size_t)sel * 1024 + local;
  }
  const float scale = (sel == 0) ? QSCL : 1.0f;
  if (fp32) {
    const float* s = (const float*)src + local;
    u32x4 w;
#pragma unroll
    for (int j = 0; j < 4; ++j) w[j] = pk_bf16(s[2 * j] * scale, s[2 * j + 1] * scale);
    *(short8*)dst = __builtin_bit_cast(short8, w);
  } else {
    const u16* s = (const u16*)src + local;
    if (sel == 0) {
      u32x4 w;
#pragma unroll
      for (int j = 0; j < 4; ++j)
        w[j] = pk_bf16(bf2f(s[2 * j]) * scale, bf2f(s[2 * j + 1]) * scale);
      *(short8*)dst = __builtin_bit_cast(short8, w);
    } else {
      *(short8*)dst = *(const short8*)s;
    }
  }
}

// x convert: grid*256*8 elements from src element offset b*2097152; dst from 0.
__global__ __launch_bounds__(256)
void convert_x_off(const void* __restrict__ x, u16* __restrict__ dst,
                   const int* __restrict__ flag, int b)
{
  const int fp32 = *flag;
  const size_t base = ((size_t)blockIdx.x * 256 + threadIdx.x) * 8;
  const size_t src_e = (size_t)b * 2048 * 1024 + base;
  if (fp32) {
    const float* s = (const float*)x + src_e;
    u32x4 w;
#pragma unroll
    for (int j = 0; j < 4; ++j) w[j] = pk_bf16(s[2 * j], s[2 * j + 1]);
    *(short8*)(dst + base) = __builtin_bit_cast(short8, w);
  } else {
    *(short8*)(dst + base) = *(const short8*)((const u16*)x + src_e);
  }
}

// ---------------------------------------------------------------------------
// GEMM (bf16 in/out): C[m,n] = sum_k A[m,k]*B[n,k] + bias[sel*1024 + n%1024].
// 128x128 tile, BK=32, 4 waves each 64x64 (m97 structure).
// r9: blockIdx.x = m-tile (fast) so concurrent blocks share one B panel in L2.
// ---------------------------------------------------------------------------
__global__ __launch_bounds__(256)
void gemm_bt(const u16* __restrict__ A,
             const u16* __restrict__ B0, const u16* __restrict__ B1, const u16* __restrict__ B2,
             const u16* __restrict__ bias, u16* __restrict__ C, int Ntot, int K)
{
  __shared__ __align__(16) u16 Alds[128 * 32];
  __shared__ __align__(16) u16 Blds[128 * 32];
  const int tid  = threadIdx.x;
  const int wave = tid >> 6, lane = tid & 63;
  const int quad = lane >> 4, l15 = lane & 15;
  const int m0  = blockIdx.x * 128;        // m fast-varying (L2 B-panel reuse)
  const int n0g = blockIdx.y * 128;
  const int sel = n0g >> 10;
  const u16* Bm = (sel == 0) ? B0 : ((sel == 1) ? B1 : B2);
  const u16* bb = bias + (size_t)sel * 1024;
  const int n0 = n0g & 1023;
  const int wr = (wave >> 1) * 64, wc = (wave & 1) * 64;

  f32x4 acc[4][4] = {};
  const int srow = lane >> 2;        // 0..15
  const int skc  = (lane & 3) * 8;   // 16B k-chunk
  const u16* Ag = A  + (size_t)(m0 + srow) * K + skc;
  const u16* Bg = Bm + (size_t)(n0 + srow) * K + skc;

  for (int kt = 0; kt < K; kt += 32) {
    __syncthreads();
#pragma unroll
    for (int t = 0; t < 2; ++t) {
      const int seg = wave * 2 + t;
      GLD_LDS(Ag + (size_t)(seg * 16) * K + kt, Alds + seg * 512);
      GLD_LDS(Bg + (size_t)(seg * 16) * K + kt, Blds + seg * 512);
    }
    __syncthreads();

    short8 af[4], bfr[4];
#pragma unroll
    for (int i = 0; i < 4; ++i)
      af[i] = *(const short8*)&Alds[(wr + i * 16 + l15) * 32 + quad * 8];
#pragma unroll
    for (int j = 0; j < 4; ++j)
      bfr[j] = *(const short8*)&Blds[(wc + j * 16 + l15) * 32 + quad * 8];
#pragma unroll
    for (int i = 0; i < 4; ++i)
#pragma unroll
      for (int j = 0; j < 4; ++j)
        acc[i][j] = __builtin_amdgcn_mfma_f32_16x16x32_bf16(af[i], bfr[j], acc[i][j], 0, 0, 0);
  }

#pragma unroll
  for (int i = 0; i < 4; ++i) {
    const int mr = m0 + wr + i * 16 + quad * 4;
#pragma unroll
    for (int j = 0; j < 4; ++j) {
      const int ncl = wc + j * 16 + l15;
      const float bvv = bf2f(bb[n0 + ncl]);
#pragma unroll
      for (int r = 0; r < 4; ++r)
        C[(size_t)(mr + r) * Ntot + n0g + ncl] = f2bf(acc[i][j][r] + bvv);
    }
  }
}

// ---------------------------------------------------------------------------
// Out-proj GEMM: writes d_out in dtype chosen by *flag. m-tile fast (r9).
// ---------------------------------------------------------------------------
__global__ __launch_bounds__(256)
void gemm_bt_out(const u16* __restrict__ A, const u16* __restrict__ Bm,
                 const u16* __restrict__ bias, void* __restrict__ C16,
                 void* __restrict__ C32, int Ntot, int K, const int* __restrict__ flag)
{
  __shared__ __align__(16) u16 Alds[128 * 32];
  __shared__ __align__(16) u16 Blds[128 * 32];
  const int tid  = threadIdx.x;
  const int wave = tid >> 6, lane = tid & 63;
  const int quad = lane >> 4, l15 = lane & 15;
  const int m0 = blockIdx.x * 128;
  const int n0 = blockIdx.y * 128;
  const int wr = (wave >> 1) * 64, wc = (wave & 1) * 64;

  f32x4 acc[4][4] = {};
  const int srow = lane >> 2;
  const int skc  = (lane & 3) * 8;
  const u16* Ag = A  + (size_t)(m0 + srow) * K + skc;
  const u16* Bg = Bm + (size_t)(n0 + srow) * K + skc;

  for (int kt = 0; kt < K; kt += 32) {
    __syncthreads();
#pragma unroll
    for (int t = 0; t < 2; ++t) {
      const int seg = wave * 2 + t;
      GLD_LDS(Ag + (size_t)(seg * 16) * K + kt, Alds + seg * 512);
      GLD_LDS(Bg + (size_t)(seg * 16) * K + kt, Blds + seg * 512);
    }
    __syncthreads();

    short8 af[4], bfr[4];
#pragma unroll
    for (int i = 0; i < 4; ++i)
      af[i] = *(const short8*)&Alds[(wr + i * 16 + l15) * 32 + quad * 8];
#pragma unroll
    for (int j = 0; j < 4; ++j)
      bfr[j] = *(const short8*)&Blds[(wc + j * 16 + l15) * 32 + quad * 8];
#pragma unroll
    for (int i = 0; i < 4; ++i)
#pragma unroll
      for (int j = 0; j < 4; ++j)
        acc[i][j] = __builtin_amdgcn_mfma_f32_16x16x32_bf16(af[i], bfr[j], acc[i][j], 0, 0, 0);
  }

  if (*flag != 0) {
    float* Cf = (float*)C32;
#pragma unroll
    for (int i = 0; i < 4; ++i) {
      const int mr = m0 + wr + i * 16 + quad * 4;
#pragma unroll
      for (int j = 0; j < 4; ++j) {
        const int ncl = wc + j * 16 + l15;
        const float bvv = bf2f(bias[n0 + ncl]);
#pragma unroll
        for (int r = 0; r < 4; ++r)
          Cf[(size_t)(mr + r) * Ntot + n0 + ncl] = acc[i][j][r] + bvv;
      }
    }
  } else {
    u16* Cb = (u16*)C16;
#pragma unroll
    for (int i = 0; i < 4; ++i) {
      const int mr = m0 + wr + i * 16 + quad * 4;
#pragma unroll
      for (int j = 0; j < 4; ++j) {
        const int ncl = wc + j * 16 + l15;
        const float bvv = bf2f(bias[n0 + ncl]);
#pragma unroll
        for (int r = 0; r < 4; ++r)
          Cb[(size_t)(mr + r) * Ntot + n0 + ncl] = f2bf(acc[i][j][r] + bvv);
      }
    }
  }
}

// ---------------------------------------------------------------------------
// Flash attention, S^T formulation (register-resident P). Q pre-scaled by
// QSCL at the projection, so exp2 applies directly to sacc.
//
// r12 post-mortem: 512-thread staging spread = EXACTLY ZERO change (118.9 vs
// 118.7us) -> the stage phase is LATENCY-bound (one load round-trip between
// two barriers), not throughput-bound. Pipelining is compiler-inaccessible
// (r5/r7/r11 all spilled). Remaining lever: reduce the COUNT of latency
// exposures.
// r13: KVBLK 64 -> 128. 16 stage phases instead of 32 (same total staging
// work: 2 K chunks + 2 V pair-packs/thread). Per-ct fused compute (ct=0..7:
// 2 ds_read -> 4 QK MFMA -> exp2/pack -> 8 PV MFMA) keeps VGPR flat — no
// sacc[8][2] materialization. Row-sum shfl reduce deferred to after the
// loop (shuffle is linear). LDS 17->34KB, still 2 blocks/CU.
// Tripwire: WRITE >> 20MB = spill => revert to r12.
// ---------------------------------------------------------------------------
__global__ __launch_bounds__(512, 4)
void attn_s(const u16* __restrict__ QKV, u16* __restrict__ O)
{
  __shared__ __align__(16) u16 Klds[128 * 72];           // [kv][d], padded
  __shared__ __align__(16) unsigned int Vlds[64 * 64];   // V^T pairs, swizzled
  const int tid  = threadIdx.x;
  const int wave = tid >> 6, lane = tid & 63;
  const int quad = lane >> 4, l15 = lane & 15;

  // XCD-panel swizzle: all 8 qt of a panel -> same XCD, consecutive slots.
  const int i  = blockIdx.x;
  const int j  = i >> 3;
  const int qt = j & 7;
  const int g  = (i & 7) + ((j >> 3) << 3);      // panel id = h + 16*z
  const int h  = g & 15;
  const int z  = g >> 4;

  const u16* QKVb = QKV + (size_t)z * 2048 * 3072;
  u16* Ob = O + (size_t)z * 2048 * 1024;
  const int q0 = qt * 256;

  // Q fragments (B-operand of x32: n=l15 -> q, k=quad*8+jj -> d)
  short8 qf[2][2];
  const u16* Qb = QKVb + (size_t)(q0 + wave * 32) * 3072 + h * 64;
#pragma unroll
  for (int rt = 0; rt < 2; ++rt)
#pragma unroll
    for (int kh = 0; kh < 2; ++kh)
      qf[rt][kh] = *(const short8*)(Qb + (size_t)(rt * 16 + l15) * 3072 + kh * 32 + quad * 8);

  f32x4 oaccT[4][2] = {};    // [dt][rt]: C[m=d_local][n=q]
  float rsp[2] = {};         // per-lane row-sum partials (reduced at end)

  // staging ids — all 512 threads, KVBLK=128:
  //  K: rows tid>>3 and tid>>3+64, 16B chunk tid&7; LDS [row][72]
  //  V: pairs p1=tid>>4 and p1+32 (kv rows 2p,2p+1), d-group (tid&15)*4
  const int kwoff = (tid >> 3) * 72 + (tid & 7) * 8;
  const int d0v = (tid & 15) * 4;
  const int kb1 = tid >> 5;            // p1>>1, 0..15
  const int kl1 = (tid >> 4) & 1;      // p1&1

  const u16* kgp = QKVb + 1024 + h * 64 + (size_t)(tid >> 3) * 3072 + (tid & 7) * 8;
  const u16* vgp = QKVb + 2048 + h * 64 + (size_t)(2 * (tid >> 4)) * 3072 + d0v;
  const size_t ADV = (size_t)128 * 3072;

  for (int kv0 = 0; kv0 < 2048; kv0 += 128) {
    __syncthreads();
    {
      *(short8*)&Klds[kwoff]           = *(const short8*)kgp;
      *(short8*)&Klds[kwoff + 64 * 72] = *(const short8*)(kgp + (size_t)64 * 3072);
      const sv4 v0 = *(const sv4*)vgp;
      const sv4 v1 = *(const sv4*)(vgp + 3072);
      const sv4 v2 = *(const sv4*)(vgp + (size_t)64 * 3072);
      const sv4 v3 = *(const sv4*)(vgp + (size_t)65 * 3072);
#pragma unroll
      for (int jj = 0; jj < 4; ++jj) {
        const int d = d0v + jj;
        const int bidx = d * 64 + ((kb1 ^ (d & 15)) << 1) + kl1;
        Vlds[bidx] =
            ((unsigned int)(unsigned short)v0[jj]) |
            (((unsigned int)(unsigned short)v1[jj]) << 16);
        Vlds[bidx + 32] =                       // kb2 = kb1+16 -> idx +32
            ((unsigned int)(unsigned short)v2[jj]) |
            (((unsigned int)(unsigned short)v3[jj]) << 16);
      }
      kgp += ADV; vgp += ADV;
    }
    __syncthreads();

    // per-ct fused: QK (x32) -> exp2/pack -> PV (x16); kv = ct*16+quad*4+r
#pragma unroll
    for (int ct = 0; ct < 8; ++ct) {
      const short8 kf0 = *(const short8*)&Klds[(ct * 16 + l15) * 72 + quad * 8];
      const short8 kf1 = *(const short8*)&Klds[(ct * 16 + l15) * 72 + 32 + quad * 8];
      __builtin_amdgcn_s_setprio(1);
      f32x4 s0 = {}, s1 = {};
      s0 = __builtin_amdgcn_mfma_f32_16x16x32_bf16(kf0, qf[0][0], s0, 0, 0, 0);
      s0 = __builtin_amdgcn_mfma_f32_16x16x32_bf16(kf1, qf[0][1], s0, 0, 0, 0);
      s1 = __builtin_amdgcn_mfma_f32_16x16x32_bf16(kf0, qf[1][0], s1, 0, 0, 0);
      s1 = __builtin_amdgcn_mfma_f32_16x16x32_bf16(kf1, qf[1][1], s1, 0, 0, 0);
      __builtin_amdgcn_s_setprio(0);

      sv4 p16[2];
      {
        float p0 = __builtin_amdgcn_exp2f(s0[0]);
        float p1 = __builtin_amdgcn_exp2f(s0[1]);
        float p2 = __builtin_amdgcn_exp2f(s0[2]);
        float p3 = __builtin_amdgcn_exp2f(s0[3]);
        rsp[0] += (p0 + p1) + (p2 + p3);
        u32x2 pw; pw[0] = pk_bf16(p0, p1); pw[1] = pk_bf16(p2, p3);
        p16[0] = __builtin_bit_cast(sv4, pw);
      }
      {
        float p0 = __builtin_amdgcn_exp2f(s1[0]);
        float p1 = __builtin_amdgcn_exp2f(s1[1]);
        float p2 = __builtin_amdgcn_exp2f(s1[2]);
        float p3 = __builtin_amdgcn_exp2f(s1[3]);
        rsp[1] += (p0 + p1) + (p2 + p3);
        u32x2 pw; pw[0] = pk_bf16(p0, p1); pw[1] = pk_bf16(p2, p3);
        p16[1] = __builtin_bit_cast(sv4, pw);
      }

      __builtin_amdgcn_s_setprio(1);
#pragma unroll
      for (int dt = 0; dt < 4; ++dt) {
        const int d = dt * 16 + l15;
        const int idx = d * 64 + (((ct * 4 + quad) ^ (d & 15)) << 1);
        const sv4 vfr = *(const sv4*)&Vlds[idx];   // kv = ct*16+quad*4 .. +3
        oaccT[dt][0] = mfma_16x16x16_bf16(vfr, p16[0], oaccT[dt][0]);
        oaccT[dt][1] = mfma_16x16x16_bf16(vfr, p16[1], oaccT[dt][1]);
      }
      __builtin_amdgcn_s_setprio(0);
    }
  }

  // deferred row-sum reduce (shuffle is linear over tile partials)
  float lrow[2];
#pragma unroll
  for (int rt = 0; rt < 2; ++rt) {
    float rs = rsp[rt];
    rs += __shfl_xor(rs, 16, 64);
    rs += __shfl_xor(rs, 32, 64);
    lrow[rt] = rs;
  }

  // store O[q][d]: q = q0+wave*32+rt*16+l15 (col), d = dt*16+quad*4+r (row)
#pragma unroll
  for (int rt = 0; rt < 2; ++rt) {
    const float inv = 1.f / lrow[rt];
    u16* Op = Ob + (size_t)(q0 + wave * 32 + rt * 16 + l15) * 1024 + h * 64;
#pragma unroll
    for (int dt = 0; dt < 4; ++dt) {
      u32x2 ow;
      ow[0] = pk_bf16(oaccT[dt][rt][0] * inv, oaccT[dt][rt][1] * inv);
      ow[1] = pk_bf16(oaccT[dt][rt][2] * inv, oaccT[dt][rt][3] * inv);
      *(sv4*)(Op + dt * 16 + quad * 4) = __builtin_bit_cast(sv4, ow);
    }
  }
}

// ---------------------------------------------------------------------------
extern "C" void kernel_launch(void* const* d_in, const int* in_sizes, int n_in,
                              void* d_out, int out_size, void* d_ws, size_t ws_size,
                              hipStream_t stream)
{
  // Common: flag + converted weights.
  int* flag = (int*)d_ws;
  u16* Wc   = (u16*)((char*)d_ws + 256);
  u16* bc   = Wc + (size_t)4 * 1048576;           // 4M u16
  char* after_wb = (char*)(bc + 4096);

  detect_dtype<<<1, 64, 0, stream>>>((const u16*)d_in[0], flag);
  convert_wb<<<2050, 256, 0, stream>>>(d_in[1], d_in[3], d_in[5], d_in[7],
                                       d_in[2], d_in[4], d_in[6], d_in[8],
                                       Wc, bc, flag);

  const size_t need_batched =
      (size_t)(after_wb - (char*)d_ws) + ((size_t)8192 * 3072 + (size_t)8192 * 1024) * 2;

  if (ws_size >= need_batched) {
    // ---- batched path: one launch per stage, full-device grids ----
    u16* QKV = (u16*)after_wb;
    u16* xO  = QKV + (size_t)8192 * 3072;   // xc before QKV-GEMM; O after attn

    convert_x_off<<<4096, 256, 0, stream>>>(d_in[0], xO, flag, 0);
    gemm_bt<<<dim3(64, 24), 256, 0, stream>>>(xO, Wc, Wc + 1048576, Wc + 2097152,
                                              bc, QKV, 3072, 1024);
    attn_s<<<512, 512, 0, stream>>>(QKV, xO);
    gemm_bt_out<<<dim3(64, 8), 256, 0, stream>>>(xO, Wc + (size_t)3 * 1048576,
                                                 bc + 3 * 1024, d_out, d_out,
                                                 1024, 1024, flag);
  } else {
    // ---- fallback: per-batch path (ws ~29.4 MB, proven) ----
    u16* xc   = (u16*)after_wb;
    u16* QKVb = xc + (size_t)2048 * 1024;
    u16* Obb  = QKVb + (size_t)2048 * 3072;
    for (int b = 0; b < 4; ++b) {
      convert_x_off<<<1024, 256, 0, stream>>>(d_in[0], xc, flag, b);
      gemm_bt<<<dim3(16, 24), 256, 0, stream>>>(xc, Wc, Wc + 1048576, Wc + 2097152,
                                                bc, QKVb, 3072, 1024);
      attn_s<<<128, 512, 0, stream>>>(QKVb, Obb);
      void* outb16 = (void*)((char*)d_out + (size_t)b * 2048 * 1024 * 2);
      void* outb32 = (void*)((char*)d_out + (size_t)b * 2048 * 1024 * 4);
      gemm_bt_out<<<dim3(16, 8), 256, 0, stream>>>(Obb, Wc + (size_t)3 * 1048576,
                                                   bc + 3 * 1024, outb16, outb32,
                                                   1024, 1024, flag);
    }
  }
}

// Round 14
// 290.329 us; speedup vs baseline: 1.3109x; 1.0421x over previous
//
#include <hip/hip_runtime.h>
#include <cstdint>
#include <cstddef>

typedef unsigned short u16;
typedef __attribute__((ext_vector_type(8))) short short8;
typedef __attribute__((ext_vector_type(4))) short sv4;    // 4 bf16 frag
typedef __attribute__((ext_vector_type(4))) float f32x4;
typedef __attribute__((ext_vector_type(2))) unsigned int u32x2;
typedef __attribute__((ext_vector_type(4))) unsigned int u32x4;

__device__ __forceinline__ u16 f2bf(float f) {
  unsigned int u = __builtin_bit_cast(unsigned int, f);
  u += 0x7FFFu + ((u >> 16) & 1u);
  return (u16)(u >> 16);
}
__device__ __forceinline__ float bf2f(u16 v) {
  return __builtin_bit_cast(float, ((unsigned int)v) << 16);
}

// packed f32x2 -> bf16x2 (RNE). gfx950 has v_cvt_pk_bf16_f32; guard builtin
// probe with __HIP_DEVICE_COMPILE__ (host pass reports no amdgcn builtins, r7).
__device__ __forceinline__ unsigned int pk_bf16(float a, float b) {
#if defined(__HIP_DEVICE_COMPILE__) && __has_builtin(__builtin_amdgcn_cvt_pk_bf16_f32)
  typedef __attribute__((ext_vector_type(2))) __bf16 bf16x2;
  bf16x2 r = __builtin_amdgcn_cvt_pk_bf16_f32(a, b);
  return __builtin_bit_cast(unsigned int, r);
#else
  return (unsigned int)f2bf(a) | ((unsigned int)f2bf(b) << 16);
#endif
}

// 16x16x16 bf16 MFMA (device-gated probe — r7 lesson).
__device__ __forceinline__ f32x4 mfma_16x16x16_bf16(sv4 a, sv4 b, f32x4 c) {
#if defined(__HIP_DEVICE_COMPILE__)
#if __has_builtin(__builtin_amdgcn_mfma_f32_16x16x16bf16_1k)
  return __builtin_amdgcn_mfma_f32_16x16x16bf16_1k(a, b, c, 0, 0, 0);
#elif __has_builtin(__builtin_amdgcn_mfma_f32_16x16x16_bf16)
  return __builtin_amdgcn_mfma_f32_16x16x16_bf16(a, b, c, 0, 0, 0);
#else
  asm volatile("v_mfma_f32_16x16x16_bf16 %0, %1, %2, %0\n\ts_nop 7\n\ts_nop 4"
               : "+v"(c) : "v"(a), "v"(b));
  return c;
#endif
#else
  (void)a; (void)b;
  return c;   // host stub, never executed
#endif
}

// async global->LDS, 16B per lane; LDS dest = wave-uniform base + lane*16
#define GLD_LDS(g, l) __builtin_amdgcn_global_load_lds( \
    (const __attribute__((address_space(1))) void*)(g), \
    (__attribute__((address_space(3))) void*)(l), 16, 0, 0)

// (1/8) * log2(e): folded into Wq/bq at convert time so attn's exp2 needs no mul
#define QSCL 0.18033688011112042f

// ---------------------------------------------------------------------------
// dtype probe: flag 1 = fp32 inputs (established on this harness), 0 = bf16.
// ---------------------------------------------------------------------------
__global__ void detect_dtype(const u16* __restrict__ x, int* __restrict__ flag)
{
  const int lane = threadIdx.x;          // 64 threads
  int hit = 0;
#pragma unroll
  for (int j = 0; j < 4; ++j) {
    float v = bf2f(x[lane * 4 + j]);
    if (!(v > -1000.f && v < 1000.f)) hit = 1;
  }
  unsigned long long any = __ballot(hit != 0);
  if (lane == 0) *flag = (any != 0ull) ? 1 : 0;
}

// ---------------------------------------------------------------------------
// Convert weights+biases to bf16: Wc=[Wq|Wk|Wv|Wo], bc=[bq|bk|bv|bo].
// Wq and bq are pre-scaled by QSCL (softmax scale fold).
// ---------------------------------------------------------------------------
__global__ __launch_bounds__(256)
void convert_wb(const void* Wq, const void* Wk, const void* Wv, const void* Wo,
                const void* bq, const void* bk, const void* bv, const void* bo,
                u16* __restrict__ Wc, u16* __restrict__ bc, const int* __restrict__ flag)
{
  const int fp32 = *flag;
  const size_t base = ((size_t)blockIdx.x * 256 + threadIdx.x) * 8;
  const void* src; u16* dst; size_t local; int sel;
  if (base < (size_t)4 * 1048576) {
    sel = (int)(base >> 20);
    local = base & 1048575u;
    src = (sel == 0) ? Wq : (sel == 1) ? Wk : (sel == 2) ? Wv : Wo;
    dst = Wc + (size_t)sel * 1048576 + local;
  } else {
    const size_t rem = base - (size_t)4 * 1048576;   // 0..4095
    sel = (int)(rem >> 10);
    local = rem & 1023u;
    src = (sel == 0) ? bq : (sel == 1) ? bk : (sel == 2) ? bv : bo;
    dst = bc + (size_t)sel * 1024 + local;
  }
  const float scale = (sel == 0) ? QSCL : 1.0f;
  if (fp32) {
    const float* s = (const float*)src + local;
    u32x4 w;
#pragma unroll
    for (int j = 0; j < 4; ++j) w[j] = pk_bf16(s[2 * j] * scale, s[2 * j + 1] * scale);
    *(short8*)dst = __builtin_bit_cast(short8, w);
  } else {
    const u16* s = (const u16*)src + local;
    if (sel == 0) {
      u32x4 w;
#pragma unroll
      for (int j = 0; j < 4; ++j)
        w[j] = pk_bf16(bf2f(s[2 * j]) * scale, bf2f(s[2 * j + 1]) * scale);
      *(short8*)dst = __builtin_bit_cast(short8, w);
    } else {
      *(short8*)dst = *(const short8*)s;
    }
  }
}

// x convert: grid*256*8 elements from src element offset b*2097152; dst from 0.
__global__ __launch_bounds__(256)
void convert_x_off(const void* __restrict__ x, u16* __restrict__ dst,
                   const int* __restrict__ flag, int b)
{
  const int fp32 = *flag;
  const size_t base = ((size_t)blockIdx.x * 256 + threadIdx.x) * 8;
  const size_t src_e = (size_t)b * 2048 * 1024 + base;
  if (fp32) {
    const float* s = (const float*)x + src_e;
    u32x4 w;
#pragma unroll
    for (int j = 0; j < 4; ++j) w[j] = pk_bf16(s[2 * j], s[2 * j + 1]);
    *(short8*)(dst + base) = __builtin_bit_cast(short8, w);
  } else {
    *(short8*)(dst + base) = *(const short8*)((const u16*)x + src_e);
  }
}

// ---------------------------------------------------------------------------
// GEMM (bf16 in/out): C[m,n] = sum_k A[m,k]*B[n,k] + bias[sel*1024 + n%1024].
// 128x128 tile, 4 waves each 64x64 (m97 structure).
// r14: BK 32 -> 64 — halves the count of barrier vmcnt-drain exposures
// (the known ~20% structural stall of the 2-phase shape; r13's lesson:
// reduce exposure COUNT). 128B LDS rows would be a 32-way read conflict,
// so staging uses the rule-#21 pattern proven in attn r2/r11: linear LDS
// dest via gload_lds + per-lane global source chunk XOR (c ^= row&7);
// fragment reads fold the same XOR (swz = ((kh*4+quad)^(l15&7))<<3) ->
// conflict-free. Same total gload count (8/wave/step x 16 steps).
// ---------------------------------------------------------------------------
__global__ __launch_bounds__(256)
void gemm_bt(const u16* __restrict__ A,
             const u16* __restrict__ B0, const u16* __restrict__ B1, const u16* __restrict__ B2,
             const u16* __restrict__ bias, u16* __restrict__ C, int Ntot, int K)
{
  __shared__ __align__(16) u16 Alds[128 * 64];
  __shared__ __align__(16) u16 Blds[128 * 64];
  const int tid  = threadIdx.x;
  const int wave = tid >> 6, lane = tid & 63;
  const int quad = lane >> 4, l15 = lane & 15;
  const int m0  = blockIdx.x * 128;        // m fast-varying (L2 B-panel reuse)
  const int n0g = blockIdx.y * 128;
  const int sel = n0g >> 10;
  const u16* Bm = (sel == 0) ? B0 : ((sel == 1) ? B1 : B2);
  const u16* bb = bias + (size_t)sel * 1024;
  const int n0 = n0g & 1023;
  const int wr = (wave >> 1) * 64, wc = (wave & 1) * 64;

  f32x4 acc[4][4] = {};
  // staging: gload seg covers 8 rows x 8 chunks; lane -> (row=lane>>3, c=lane&7),
  // global chunk swizzled c^row (row&7 == lane>>3 since seg*8 is 8-aligned)
  const int arow = lane >> 3;                       // 0..7
  const int ac8  = (((lane & 7) ^ arow) << 3);      // swizzled 16B chunk, u16 units
  const u16* Ag = A  + (size_t)(m0 + arow) * K + ac8;
  const u16* Bg = Bm + (size_t)(n0 + arow) * K + ac8;

  for (int kt = 0; kt < K; kt += 64) {
    __syncthreads();
#pragma unroll
    for (int t = 0; t < 4; ++t) {
      const int seg = wave * 4 + t;
      GLD_LDS(Ag + (size_t)(seg * 8) * K + kt, Alds + seg * 512);
      GLD_LDS(Bg + (size_t)(seg * 8) * K + kt, Blds + seg * 512);
    }
    __syncthreads();

#pragma unroll
    for (int kh = 0; kh < 2; ++kh) {
      const int swz = (((kh * 4 + quad) ^ (l15 & 7)) << 3);
      short8 af[4], bfr[4];
#pragma unroll
      for (int i = 0; i < 4; ++i)
        af[i] = *(const short8*)&Alds[(wr + i * 16 + l15) * 64 + swz];
#pragma unroll
      for (int j = 0; j < 4; ++j)
        bfr[j] = *(const short8*)&Blds[(wc + j * 16 + l15) * 64 + swz];
#pragma unroll
      for (int i = 0; i < 4; ++i)
#pragma unroll
        for (int j = 0; j < 4; ++j)
          acc[i][j] = __builtin_amdgcn_mfma_f32_16x16x32_bf16(af[i], bfr[j], acc[i][j], 0, 0, 0);
    }
  }

#pragma unroll
  for (int i = 0; i < 4; ++i) {
    const int mr = m0 + wr + i * 16 + quad * 4;
#pragma unroll
    for (int j = 0; j < 4; ++j) {
      const int ncl = wc + j * 16 + l15;
      const float bvv = bf2f(bb[n0 + ncl]);
#pragma unroll
      for (int r = 0; r < 4; ++r)
        C[(size_t)(mr + r) * Ntot + n0g + ncl] = f2bf(acc[i][j][r] + bvv);
    }
  }
}

// ---------------------------------------------------------------------------
// Out-proj GEMM: writes d_out in dtype chosen by *flag. Same r14 BK=64 shape.
// ---------------------------------------------------------------------------
__global__ __launch_bounds__(256)
void gemm_bt_out(const u16* __restrict__ A, const u16* __restrict__ Bm,
                 const u16* __restrict__ bias, void* __restrict__ C16,
                 void* __restrict__ C32, int Ntot, int K, const int* __restrict__ flag)
{
  __shared__ __align__(16) u16 Alds[128 * 64];
  __shared__ __align__(16) u16 Blds[128 * 64];
  const int tid  = threadIdx.x;
  const int wave = tid >> 6, lane = tid & 63;
  const int quad = lane >> 4, l15 = lane & 15;
  const int m0 = blockIdx.x * 128;
  const int n0 = blockIdx.y * 128;
  const int wr = (wave >> 1) * 64, wc = (wave & 1) * 64;

  f32x4 acc[4][4] = {};
  const int arow = lane >> 3;
  const int ac8  = (((lane & 7) ^ arow) << 3);
  const u16* Ag = A  + (size_t)(m0 + arow) * K + ac8;
  const u16* Bg = Bm + (size_t)(n0 + arow) * K + ac8;

  for (int kt = 0; kt < K; kt += 64) {
    __syncthreads();
#pragma unroll
    for (int t = 0; t < 4; ++t) {
      const int seg = wave * 4 + t;
      GLD_LDS(Ag + (size_t)(seg * 8) * K + kt, Alds + seg * 512);
      GLD_LDS(Bg + (size_t)(seg * 8) * K + kt, Blds + seg * 512);
    }
    __syncthreads();

#pragma unroll
    for (int kh = 0; kh < 2; ++kh) {
      const int swz = (((kh * 4 + quad) ^ (l15 & 7)) << 3);
      short8 af[4], bfr[4];
#pragma unroll
      for (int i = 0; i < 4; ++i)
        af[i] = *(const short8*)&Alds[(wr + i * 16 + l15) * 64 + swz];
#pragma unroll
      for (int j = 0; j < 4; ++j)
        bfr[j] = *(const short8*)&Blds[(wc + j * 16 + l15) * 64 + swz];
#pragma unroll
      for (int i = 0; i < 4; ++i)
#pragma unroll
        for (int j = 0; j < 4; ++j)
          acc[i][j] = __builtin_amdgcn_mfma_f32_16x16x32_bf16(af[i], bfr[j], acc[i][j], 0, 0, 0);
    }
  }

  if (*flag != 0) {
    float* Cf = (float*)C32;
#pragma unroll
    for (int i = 0; i < 4; ++i) {
      const int mr = m0 + wr + i * 16 + quad * 4;
#pragma unroll
      for (int j = 0; j < 4; ++j) {
        const int ncl = wc + j * 16 + l15;
        const float bvv = bf2f(bias[n0 + ncl]);
#pragma unroll
        for (int r = 0; r < 4; ++r)
          Cf[(size_t)(mr + r) * Ntot + n0 + ncl] = acc[i][j][r] + bvv;
      }
    }
  } else {
    u16* Cb = (u16*)C16;
#pragma unroll
    for (int i = 0; i < 4; ++i) {
      const int mr = m0 + wr + i * 16 + quad * 4;
#pragma unroll
      for (int j = 0; j < 4; ++j) {
        const int ncl = wc + j * 16 + l15;
        const float bvv = bf2f(bias[n0 + ncl]);
#pragma unroll
        for (int r = 0; r < 4; ++r)
          Cb[(size_t)(mr + r) * Ntot + n0 + ncl] = f2bf(acc[i][j][r] + bvv);
      }
    }
  }
}

// ---------------------------------------------------------------------------
// Flash attention — r13 kernel verbatim (112.1us, FETCH 24.6MB, proven).
// KVBLK=128, per-ct fused QK->softmax->PV, deferred row-sum reduce.
// ---------------------------------------------------------------------------
__global__ __launch_bounds__(512, 4)
void attn_s(const u16* __restrict__ QKV, u16* __restrict__ O)
{
  __shared__ __align__(16) u16 Klds[128 * 72];           // [kv][d], padded
  __shared__ __align__(16) unsigned int Vlds[64 * 64];   // V^T pairs, swizzled
  const int tid  = threadIdx.x;
  const int wave = tid >> 6, lane = tid & 63;
  const int quad = lane >> 4, l15 = lane & 15;

  // XCD-panel swizzle: all 8 qt of a panel -> same XCD, consecutive slots.
  const int i  = blockIdx.x;
  const int j  = i >> 3;
  const int qt = j & 7;
  const int g  = (i & 7) + ((j >> 3) << 3);      // panel id = h + 16*z
  const int h  = g & 15;
  const int z  = g >> 4;

  const u16* QKVb = QKV + (size_t)z * 2048 * 3072;
  u16* Ob = O + (size_t)z * 2048 * 1024;
  const int q0 = qt * 256;

  // Q fragments (B-operand of x32: n=l15 -> q, k=quad*8+jj -> d)
  short8 qf[2][2];
  const u16* Qb = QKVb + (size_t)(q0 + wave * 32) * 3072 + h * 64;
#pragma unroll
  for (int rt = 0; rt < 2; ++rt)
#pragma unroll
    for (int kh = 0; kh < 2; ++kh)
      qf[rt][kh] = *(const short8*)(Qb + (size_t)(rt * 16 + l15) * 3072 + kh * 32 + quad * 8);

  f32x4 oaccT[4][2] = {};    // [dt][rt]: C[m=d_local][n=q]
  float rsp[2] = {};         // per-lane row-sum partials (reduced at end)

  // staging ids — all 512 threads, KVBLK=128:
  //  K: rows tid>>3 and tid>>3+64, 16B chunk tid&7; LDS [row][72]
  //  V: pairs p1=tid>>4 and p1+32 (kv rows 2p,2p+1), d-group (tid&15)*4
  const int kwoff = (tid >> 3) * 72 + (tid & 7) * 8;
  const int d0v = (tid & 15) * 4;
  const int kb1 = tid >> 5;            // p1>>1, 0..15
  const int kl1 = (tid >> 4) & 1;      // p1&1

  const u16* kgp = QKVb + 1024 + h * 64 + (size_t)(tid >> 3) * 3072 + (tid & 7) * 8;
  const u16* vgp = QKVb + 2048 + h * 64 + (size_t)(2 * (tid >> 4)) * 3072 + d0v;
  const size_t ADV = (size_t)128 * 3072;

  for (int kv0 = 0; kv0 < 2048; kv0 += 128) {
    __syncthreads();
    {
      *(short8*)&Klds[kwoff]           = *(const short8*)kgp;
      *(short8*)&Klds[kwoff + 64 * 72] = *(const short8*)(kgp + (size_t)64 * 3072);
      const sv4 v0 = *(const sv4*)vgp;
      const sv4 v1 = *(const sv4*)(vgp + 3072);
      const sv4 v2 = *(const sv4*)(vgp + (size_t)64 * 3072);
      const sv4 v3 = *(const sv4*)(vgp + (size_t)65 * 3072);
#pragma unroll
      for (int jj = 0; jj < 4; ++jj) {
        const int d = d0v + jj;
        const int bidx = d * 64 + ((kb1 ^ (d & 15)) << 1) + kl1;
        Vlds[bidx] =
            ((unsigned int)(unsigned short)v0[jj]) |
            (((unsigned int)(unsigned short)v1[jj]) << 16);
        Vlds[bidx + 32] =                       // kb2 = kb1+16 -> idx +32
            ((unsigned int)(unsigned short)v2[jj]) |
            (((unsigned int)(unsigned short)v3[jj]) << 16);
      }
      kgp += ADV; vgp += ADV;
    }
    __syncthreads();

    // per-ct fused: QK (x32) -> exp2/pack -> PV (x16); kv = ct*16+quad*4+r
#pragma unroll
    for (int ct = 0; ct < 8; ++ct) {
      const short8 kf0 = *(const short8*)&Klds[(ct * 16 + l15) * 72 + quad * 8];
      const short8 kf1 = *(const short8*)&Klds[(ct * 16 + l15) * 72 + 32 + quad * 8];
      __builtin_amdgcn_s_setprio(1);
      f32x4 s0 = {}, s1 = {};
      s0 = __builtin_amdgcn_mfma_f32_16x16x32_bf16(kf0, qf[0][0], s0, 0, 0, 0);
      s0 = __builtin_amdgcn_mfma_f32_16x16x32_bf16(kf1, qf[0][1], s0, 0, 0, 0);
      s1 = __builtin_amdgcn_mfma_f32_16x16x32_bf16(kf0, qf[1][0], s1, 0, 0, 0);
      s1 = __builtin_amdgcn_mfma_f32_16x16x32_bf16(kf1, qf[1][1], s1, 0, 0, 0);
      __builtin_amdgcn_s_setprio(0);

      sv4 p16[2];
      {
        float p0 = __builtin_amdgcn_exp2f(s0[0]);
        float p1 = __builtin_amdgcn_exp2f(s0[1]);
        float p2 = __builtin_amdgcn_exp2f(s0[2]);
        float p3 = __builtin_amdgcn_exp2f(s0[3]);
        rsp[0] += (p0 + p1) + (p2 + p3);
        u32x2 pw; pw[0] = pk_bf16(p0, p1); pw[1] = pk_bf16(p2, p3);
        p16[0] = __builtin_bit_cast(sv4, pw);
      }
      {
        float p0 = __builtin_amdgcn_exp2f(s1[0]);
        float p1 = __builtin_amdgcn_exp2f(s1[1]);
        float p2 = __builtin_amdgcn_exp2f(s1[2]);
        float p3 = __builtin_amdgcn_exp2f(s1[3]);
        rsp[1] += (p0 + p1) + (p2 + p3);
        u32x2 pw; pw[0] = pk_bf16(p0, p1); pw[1] = pk_bf16(p2, p3);
        p16[1] = __builtin_bit_cast(sv4, pw);
      }

      __builtin_amdgcn_s_setprio(1);
#pragma unroll
      for (int dt = 0; dt < 4; ++dt) {
        const int d = dt * 16 + l15;
        const int idx = d * 64 + (((ct * 4 + quad) ^ (d & 15)) << 1);
        const sv4 vfr = *(const sv4*)&Vlds[idx];   // kv = ct*16+quad*4 .. +3
        oaccT[dt][0] = mfma_16x16x16_bf16(vfr, p16[0], oaccT[dt][0]);
        oaccT[dt][1] = mfma_16x16x16_bf16(vfr, p16[1], oaccT[dt][1]);
      }
      __builtin_amdgcn_s_setprio(0);
    }
  }

  // deferred row-sum reduce (shuffle is linear over tile partials)
  float lrow[2];
#pragma unroll
  for (int rt = 0; rt < 2; ++rt) {
    float rs = rsp[rt];
    rs += __shfl_xor(rs, 16, 64);
    rs += __shfl_xor(rs, 32, 64);
    lrow[rt] = rs;
  }

  // store O[q][d]: q = q0+wave*32+rt*16+l15 (col), d = dt*16+quad*4+r (row)
#pragma unroll
  for (int rt = 0; rt < 2; ++rt) {
    const float inv = 1.f / lrow[rt];
    u16* Op = Ob + (size_t)(q0 + wave * 32 + rt * 16 + l15) * 1024 + h * 64;
#pragma unroll
    for (int dt = 0; dt < 4; ++dt) {
      u32x2 ow;
      ow[0] = pk_bf16(oaccT[dt][rt][0] * inv, oaccT[dt][rt][1] * inv);
      ow[1] = pk_bf16(oaccT[dt][rt][2] * inv, oaccT[dt][rt][3] * inv);
      *(sv4*)(Op + dt * 16 + quad * 4) = __builtin_bit_cast(sv4, ow);
    }
  }
}

// ---------------------------------------------------------------------------
extern "C" void kernel_launch(void* const* d_in, const int* in_sizes, int n_in,
                              void* d_out, int out_size, void* d_ws, size_t ws_size,
                              hipStream_t stream)
{
  // Common: flag + converted weights.
  int* flag = (int*)d_ws;
  u16* Wc   = (u16*)((char*)d_ws + 256);
  u16* bc   = Wc + (size_t)4 * 1048576;           // 4M u16
  char* after_wb = (char*)(bc + 4096);

  detect_dtype<<<1, 64, 0, stream>>>((const u16*)d_in[0], flag);
  convert_wb<<<2050, 256, 0, stream>>>(d_in[1], d_in[3], d_in[5], d_in[7],
                                       d_in[2], d_in[4], d_in[6], d_in[8],
                                       Wc, bc, flag);

  const size_t need_batched =
      (size_t)(after_wb - (char*)d_ws) + ((size_t)8192 * 3072 + (size_t)8192 * 1024) * 2;

  if (ws_size >= need_batched) {
    // ---- batched path: one launch per stage, full-device grids ----
    u16* QKV = (u16*)after_wb;
    u16* xO  = QKV + (size_t)8192 * 3072;   // xc before QKV-GEMM; O after attn

    convert_x_off<<<4096, 256, 0, stream>>>(d_in[0], xO, flag, 0);
    gemm_bt<<<dim3(64, 24), 256, 0, stream>>>(xO, Wc, Wc + 1048576, Wc + 2097152,
                                              bc, QKV, 3072, 1024);
    attn_s<<<512, 512, 0, stream>>>(QKV, xO);
    gemm_bt_out<<<dim3(64, 8), 256, 0, stream>>>(xO, Wc + (size_t)3 * 1048576,
                                                 bc + 3 * 1024, d_out, d_out,
                                                 1024, 1024, flag);
  } else {
    // ---- fallback: per-batch path (ws ~29.4 MB, proven) ----
    u16* xc   = (u16*)after_wb;
    u16* QKVb = xc + (size_t)2048 * 1024;
    u16* Obb  = QKVb + (size_t)2048 * 3072;
    for (int b = 0; b < 4; ++b) {
      convert_x_off<<<1024, 256, 0, stream>>>(d_in[0], xc, flag, b);
      gemm_bt<<<dim3(16, 24), 256, 0, stream>>>(xc, Wc, Wc + 1048576, Wc + 2097152,
                                                bc, QKVb, 3072, 1024);
      attn_s<<<128, 512, 0, stream>>>(QKVb, Obb);
      void* outb16 = (void*)((char*)d_out + (size_t)b * 2048 * 1024 * 2);
      void* outb32 = (void*)((char*)d_out + (size_t)b * 2048 * 1024 * 4);
      gemm_bt_out<<<dim3(16, 8), 256, 0, stream>>>(Obb, Wc + (size_t)3 * 1048576,
                                                   bc + 3 * 1024, outb16, outb32,
                                                   1024, 1024, flag);
    }
  }
}